// Round 4
// baseline (587.002 us; speedup 1.0000x reference)
//
#include <hip/hip_runtime.h>
#include <math.h>

#define NPAR 8
#define DIM  16
#define HID  128
#define BATCH 4096
#define SPB  2                 // samples (waves) per block
#define VSTR 130               // padded stride (doubles) for 128-vectors in LDS
#define NVEC 9                 // base + 8 tangent directions
#define BUFSZ (NVEC*VSTR)      // 1170 doubles
#define SM_PER (2*BUFSZ + 16)  // two ping-pong buffers + xs (doubles)

// Packed fp64 weights in static device memory.
// Layout (double offsets): PF2@0 PB2@16384 PF3@32768 PB3@49152 PF4@65536 PB4@81920 PB1@98304
__device__ double g_ws[6*HID*HID + HID*DIM];

__device__ __forceinline__ double sigd(double z){ return 1.0/(1.0+exp(-z)); }
__device__ __forceinline__ double spd(double z){ return fmax(z,0.0)+log1p(exp(-fabs(z))); }

// PF[q][j][kk] = W[j][2q+kk]  (forward GEMV)   PB[q][j][kk] = W[2q+kk][j]  (W^T GEMV)
// PB1[q][m][kk] = W1[2q+kk][m]
__global__ void pack_weights(const float* __restrict__ W1, const float* __restrict__ W2,
                             const float* __restrict__ W3, const float* __restrict__ W4) {
  int t = blockIdx.x*blockDim.x + threadIdx.x;
  if (t < 3*HID*HID) {
    int m = t/(HID*HID); int r = t%(HID*HID);
    int j = r/HID, k = r%HID;
    const float* W = (m==0)?W2:((m==1)?W3:W4);
    double w = (double)W[j*HID+k];
    double* PF = g_ws + m*2*HID*HID;
    double* PB = PF + HID*HID;
    PF[(k>>1)*(HID*2) + j*2 + (k&1)] = w;
    PB[(j>>1)*(HID*2) + k*2 + (j&1)] = w;
  } else {
    int r = t - 3*HID*HID;
    if (r < HID*DIM) {
      int k = r/DIM, m2 = r%DIM;
      g_ws[6*HID*HID + (k>>1)*(DIM*2) + m2*2 + (k&1)] = (double)W1[k*DIM+m2];
    }
  }
}

// Fused 9-vector fp64 GEMV: acc{A,B}[v] = (W @ bin_v)[l], (W @ bin_v)[l+64]
__device__ __forceinline__ void gemv9d(const double* __restrict__ Wbase,
                                       const double* bin, int l,
                                       double* accA, double* accB) {
  const double2* Wq = (const double2*)Wbase;
#pragma unroll
  for (int v=0; v<NVEC; ++v){ accA[v]=0.0; accB[v]=0.0; }
#pragma unroll 2
  for (int q=0; q<HID/2; ++q){
    double2 wA = Wq[q*HID + l];
    double2 wB = Wq[q*HID + l + 64];
#pragma unroll
    for (int v=0; v<NVEC; ++v){
      double2 h = *((const double2*)(bin + v*VSTR + 2*q));  // LDS broadcast
      accA[v] = fma(wA.y, h.y, fma(wA.x, h.x, accA[v]));
      accB[v] = fma(wB.y, h.y, fma(wB.x, h.x, accB[v]));
    }
  }
}

__global__ __launch_bounds__(128, 2)
void lnn_main(const float* __restrict__ x, const float* __restrict__ W1,
              const float* __restrict__ b1, const float* __restrict__ b2,
              const float* __restrict__ b3, const float* __restrict__ b4,
              const float* __restrict__ W5, float* __restrict__ out) {
  const int l  = threadIdx.x & 63;
  const int wv = threadIdx.x >> 6;
  const int s  = blockIdx.x*SPB + wv;

  __shared__ __align__(16) double smem[SPB*SM_PER];
  double* bufA = smem + wv*SM_PER;
  double* bufB = bufA + BUFSZ;
  double* xs   = bufA + 2*BUFSZ;

  if (l < DIM) xs[l] = (double)x[s*DIM + l];
  __syncthreads();

  // ---- Phase 1: layer 1 ----
  const float* r0 = W1 + l*DIM;
  const float* r1 = W1 + (l+64)*DIM;
  double z1a = (double)b1[l], z1b = (double)b1[l+64];
  double w1a[8], w1b[8];          // t_z1 = W1[:,8+i]
#pragma unroll
  for (int k2=0; k2<DIM; ++k2){
    double wa = (double)r0[k2], wb = (double)r1[k2];
    z1a = fma(wa, xs[k2], z1a);
    z1b = fma(wb, xs[k2], z1b);
    if (k2 >= 8) { w1a[k2-8] = wa; w1b[k2-8] = wb; }
  }
  double s1a = sigd(z1a), s1b = sigd(z1b);
  bufA[l] = spd(z1a); bufA[l+64] = spd(z1b);
#pragma unroll
  for (int i=0;i<8;++i){
    bufA[(1+i)*VSTR + l]      = s1a*w1a[i];
    bufA[(1+i)*VSTR + l + 64] = s1b*w1b[i];
  }
  __syncthreads();

  double A9[NVEC], B9[NVEC];

  // ---- Phase 2: layer 2 forward (PF2) ----
  gemv9d(g_ws + 0, bufA, l, A9, B9);
  double z2a = A9[0] + (double)b2[l], z2b = B9[0] + (double)b2[l+64];
  double t2a[8], t2b[8];
#pragma unroll
  for (int i=0;i<8;++i){ t2a[i]=A9[1+i]; t2b[i]=B9[1+i]; }
  double s2a = sigd(z2a), s2b = sigd(z2b);
  bufB[l] = spd(z2a); bufB[l+64] = spd(z2b);
#pragma unroll
  for (int i=0;i<8;++i){
    bufB[(1+i)*VSTR + l]      = s2a*t2a[i];
    bufB[(1+i)*VSTR + l + 64] = s2b*t2b[i];
  }
  __syncthreads();

  // ---- Phase 3: layer 3 forward (PF3) ----
  gemv9d(g_ws + 32768, bufB, l, A9, B9);
  double z3a = A9[0] + (double)b3[l], z3b = B9[0] + (double)b3[l+64];
  double t3a[8], t3b[8];
#pragma unroll
  for (int i=0;i<8;++i){ t3a[i]=A9[1+i]; t3b[i]=B9[1+i]; }
  double s3a = sigd(z3a), s3b = sigd(z3b);
  bufA[l] = spd(z3a); bufA[l+64] = spd(z3b);
#pragma unroll
  for (int i=0;i<8;++i){
    bufA[(1+i)*VSTR + l]      = s3a*t3a[i];
    bufA[(1+i)*VSTR + l + 64] = s3b*t3b[i];
  }
  __syncthreads();

  // ---- Phase 4: layer 4 forward (PF4) ----
  gemv9d(g_ws + 65536, bufA, l, A9, B9);
  double z4a = A9[0] + (double)b4[l], z4b = B9[0] + (double)b4[l+64];

  // ---- Phase 5: head ----
  {
    double w5a = (double)W5[l], w5b = (double)W5[l+64];
    double sa = sigd(z4a), sb = sigd(z4b);
    bufB[l] = w5a*sa; bufB[l+64] = w5b*sb;                 // g_z4
    double ca = w5a*sa*(1.0-sa), cb = w5b*sb*(1.0-sb);     // W5*sig'(z4)
#pragma unroll
    for (int i=0;i<8;++i){
      bufB[(1+i)*VSTR + l]      = ca*A9[1+i];              // u_z4
      bufB[(1+i)*VSTR + l + 64] = cb*B9[1+i];
    }
  }
  __syncthreads();

  // ---- Phase 6: backward through W4^T (PB4) ----
  gemv9d(g_ws + 81920, bufB, l, A9, B9);
  {
    double da = s3a*(1.0-s3a)*A9[0], db = s3b*(1.0-s3b)*B9[0];
    bufA[l] = A9[0]*s3a; bufA[l+64] = B9[0]*s3b;                 // g_z3
#pragma unroll
    for (int i=0;i<8;++i){
      bufA[(1+i)*VSTR + l]      = fma(A9[1+i], s3a, da*t3a[i]);  // u_z3
      bufA[(1+i)*VSTR + l + 64] = fma(B9[1+i], s3b, db*t3b[i]);
    }
  }
  __syncthreads();

  // ---- Phase 7: backward through W3^T (PB3) ----
  gemv9d(g_ws + 49152, bufA, l, A9, B9);
  {
    double da = s2a*(1.0-s2a)*A9[0], db = s2b*(1.0-s2b)*B9[0];
    bufB[l] = A9[0]*s2a; bufB[l+64] = B9[0]*s2b;                 // g_z2
#pragma unroll
    for (int i=0;i<8;++i){
      bufB[(1+i)*VSTR + l]      = fma(A9[1+i], s2a, da*t2a[i]);  // u_z2
      bufB[(1+i)*VSTR + l + 64] = fma(B9[1+i], s2b, db*t2b[i]);
    }
  }
  __syncthreads();

  // ---- Phase 8: backward through W2^T (PB2) ----
  gemv9d(g_ws + 16384, bufB, l, A9, B9);
  {
    double da = s1a*(1.0-s1a)*A9[0], db = s1b*(1.0-s1b)*B9[0];
    bufA[l] = A9[0]*s1a; bufA[l+64] = B9[0]*s1b;                 // g_z1
#pragma unroll
    for (int i=0;i<8;++i){
      bufA[(1+i)*VSTR + l]      = fma(A9[1+i], s1a, da*w1a[i]);  // u_z1
      bufA[(1+i)*VSTR + l + 64] = fma(B9[1+i], s1b, db*w1b[i]);
    }
  }
  __syncthreads();

  // ---- Phase 9: H rows (8..15) + J via W1^T (PB1) ----
  {
    const int m = l & 15, d = l >> 4;
    const double2* P1 = (const double2*)(g_ws + 98304);
    double hA=0.0, hB=0.0, hJ=0.0;
#pragma unroll 4
    for (int q=0; q<64; ++q){
      double2 wq = P1[q*DIM + m];   // {W1[2q][m], W1[2q+1][m]}
      double2 u0 = *((const double2*)(bufA + (1+d)*VSTR + 2*q));
      double2 u1 = *((const double2*)(bufA + (5+d)*VSTR + 2*q));
      double2 gg = *((const double2*)(bufA + 2*q));
      hA = fma(wq.y, u0.y, fma(wq.x, u0.x, hA));
      hB = fma(wq.y, u1.y, fma(wq.x, u1.x, hB));
      hJ = fma(wq.y, gg.y, fma(wq.x, gg.x, hJ));
    }
    double* hr = bufB;   // hr[i*17+m] = H[8+i][m]; hr[8*17+m] = J[m]
    hr[d*17+m] = hA;
    hr[(d+4)*17+m] = hB;
    if (d==0) hr[8*17+m] = hJ;
  }
  __syncthreads();

  // ---- Phase 10: y = pinv(B) @ (J[:8] - C qdot), JAX pinv semantics ----
  // B symmetric 8x8; eigendecomp via cyclic Jacobi (lane = (r,c)), then
  // truncate |lambda| <= rcond*max|lambda|, rcond = 10*8*eps_f32 (JAX default).
  {
    double* hr = bufB;
    const int r = l >> 3, c = l & 7;
    double Bv = hr[r*17 + 8 + c];     // B[r][c]
    double Cr = hr[r*17 + c];         // C[r][c]
    double Jr = hr[8*17 + r];         // A[r]
    double p0 = Cr * xs[8 + c];
    p0 += __shfl_xor(p0, 1); p0 += __shfl_xor(p0, 2); p0 += __shfl_xor(p0, 4);
    double rhs = Jr - p0;             // all lanes of row r hold rhs_r

    // symmetrize
    double Bt = __shfl(Bv, c*8 + r);
    double Am = 0.5*(Bv + Bt);
    double Vm = (r == c) ? 1.0 : 0.0;

    for (int sweep = 0; sweep < 7; ++sweep) {
      for (int p = 0; p < 7; ++p) {
        for (int q = p+1; q < 8; ++q) {
          double Bpp = __shfl(Am, p*8+p);
          double Bqq = __shfl(Am, q*8+q);
          double Bpq = __shfl(Am, p*8+q);
          double cth = 1.0, sth = 0.0;
          if (fabs(Bpq) > 1e-280) {   // wave-uniform branch
            double tau = (Bqq - Bpp) / (2.0*Bpq);
            double tt = (tau >= 0.0 ? 1.0 : -1.0) / (fabs(tau) + sqrt(1.0 + tau*tau));
            cth = 1.0 / sqrt(1.0 + tt*tt);
            sth = tt * cth;
          }
          // column rotation: M = A*G
          double Arp = __shfl(Am, r*8+p);
          double Arq = __shfl(Am, r*8+q);
          double colv = Am;
          if (c == p) colv = cth*Arp - sth*Arq;
          if (c == q) colv = sth*Arp + cth*Arq;
          // row rotation: A = G^T * M
          double Cpc = __shfl(colv, p*8+c);
          double Cqc = __shfl(colv, q*8+c);
          double newv = colv;
          if (r == p) newv = cth*Cpc - sth*Cqc;
          if (r == q) newv = sth*Cpc + cth*Cqc;
          Am = newv;
          // V = V*G
          double Vrp = __shfl(Vm, r*8+p);
          double Vrq = __shfl(Vm, r*8+q);
          if (c == p) Vm = cth*Vrp - sth*Vrq;
          if (c == q) Vm = sth*Vrp + cth*Vrq;
        }
      }
    }

    // eigenvalue for this lane's column, and sigma_max = max |diag|
    double lam_c = __shfl(Am, c*8 + c);
    double adiag = (r == c) ? fabs(Am) : 0.0;
#pragma unroll
    for (int off = 32; off; off >>= 1) adiag = fmax(adiag, __shfl_xor(adiag, off));
    double cutoff = 9.5367431640625e-06 * adiag;   // 10*max(M,N)*eps_f32 * sigma_max

    // p_c = sum_r V[r][c]*rhs_r
    double pr = Vm * rhs;
    pr += __shfl_xor(pr, 8); pr += __shfl_xor(pr, 16); pr += __shfl_xor(pr, 32);
    double w = (fabs(lam_c) > cutoff) ? (pr / lam_c) : 0.0;
    // y_r = sum_c V[r][c]*w_c
    double yr = Vm * w;
    yr += __shfl_xor(yr, 1); yr += __shfl_xor(yr, 2); yr += __shfl_xor(yr, 4);
    if (c == 0) out[s*NPAR + r] = (float)yr;
  }
}

extern "C" void kernel_launch(void* const* d_in, const int* in_sizes, int n_in,
                              void* d_out, int out_size, void* d_ws, size_t ws_size,
                              hipStream_t stream) {
  (void)in_sizes; (void)n_in; (void)out_size; (void)d_ws; (void)ws_size;
  const float* x  = (const float*)d_in[0];
  const float* W1 = (const float*)d_in[1];
  const float* b1 = (const float*)d_in[2];
  const float* W2 = (const float*)d_in[3];
  const float* b2 = (const float*)d_in[4];
  const float* W3 = (const float*)d_in[5];
  const float* b3 = (const float*)d_in[6];
  const float* W4 = (const float*)d_in[7];
  const float* b4 = (const float*)d_in[8];
  const float* W5 = (const float*)d_in[9];
  float* out = (float*)d_out;

  pack_weights<<<200, 256, 0, stream>>>(W1, W2, W3, W4);
  lnn_main<<<BATCH/SPB, 128, 0, stream>>>(x, W1, b1, b2, b3, b4, W5, out);
}

// Round 5
// 556.248 us; speedup vs baseline: 1.0553x; 1.0553x over previous
//
#include <hip/hip_runtime.h>
#include <math.h>

#define NPAR 8
#define DIM  16
#define HID  128
#define BATCH 4096
#define VSTR 128               // stride (doubles) for 128-vectors in LDS (broadcast reads: no padding needed)
#define NVEC 9                 // base + 8 tangent directions

// Packed fp64 weights in static device memory.
// Layout (double offsets): PF2@0 PB2@16384 PF3@32768 PB3@49152 PF4@65536 PB4@81920 PB1@98304
__device__ double g_ws[6*HID*HID + HID*DIM];

__device__ __forceinline__ double sigd(double z){ return 1.0/(1.0+exp(-z)); }
__device__ __forceinline__ double spd(double z){ return fmax(z,0.0)+log1p(exp(-fabs(z))); }

// PF[q][j][kk] = W[j][2q+kk]  (forward GEMV)   PB[q][j][kk] = W[2q+kk][j]  (W^T GEMV)
// PB1[q][m][kk] = W1[2q+kk][m]
__global__ void pack_weights(const float* __restrict__ W1, const float* __restrict__ W2,
                             const float* __restrict__ W3, const float* __restrict__ W4) {
  int t = blockIdx.x*blockDim.x + threadIdx.x;
  if (t < 3*HID*HID) {
    int m = t/(HID*HID); int r = t%(HID*HID);
    int j = r/HID, k = r%HID;
    const float* W = (m==0)?W2:((m==1)?W3:W4);
    double w = (double)W[j*HID+k];
    double* PF = g_ws + m*2*HID*HID;
    double* PB = PF + HID*HID;
    PF[(k>>1)*(HID*2) + j*2 + (k&1)] = w;
    PB[(j>>1)*(HID*2) + k*2 + (j&1)] = w;
  } else {
    int r = t - 3*HID*HID;
    if (r < HID*DIM) {
      int k = r/DIM, m2 = r%DIM;
      g_ws[6*HID*HID + (k>>1)*(DIM*2) + m2*2 + (k&1)] = (double)W1[k*DIM+m2];
    }
  }
}

// Fused 9-vector fp64 GEMV: acc{A,B}[v] = (W @ bin_v)[l], (W @ bin_v)[l+64]
__device__ __forceinline__ void gemv9d(const double* __restrict__ Wbase,
                                       const double* bin, int l,
                                       double* accA, double* accB) {
  const double2* Wq = (const double2*)Wbase;
#pragma unroll
  for (int v=0; v<NVEC; ++v){ accA[v]=0.0; accB[v]=0.0; }
#pragma unroll 2
  for (int q=0; q<HID/2; ++q){
    double2 wA = Wq[q*HID + l];
    double2 wB = Wq[q*HID + l + 64];
#pragma unroll
    for (int v=0; v<NVEC; ++v){
      double2 h = *((const double2*)(bin + v*VSTR + 2*q));  // LDS broadcast
      accA[v] = fma(wA.y, h.y, fma(wA.x, h.x, accA[v]));
      accB[v] = fma(wB.y, h.y, fma(wB.x, h.x, accB[v]));
    }
  }
}

__global__ __launch_bounds__(64, 4)
void lnn_main(const float* __restrict__ x, const float* __restrict__ W1,
              const float* __restrict__ b1, const float* __restrict__ b2,
              const float* __restrict__ b3, const float* __restrict__ b4,
              const float* __restrict__ W5, float* __restrict__ out) {
  const int l = threadIdx.x;           // one wave per block
  const int s = blockIdx.x;            // one sample per wave

  __shared__ __align__(16) double buf[NVEC*VSTR];  // single in-place buffer (1152 d)
  __shared__ __align__(16) double hr[160];         // H-rows + J scratch
  __shared__ double xs[16];

  if (l < DIM) xs[l] = (double)x[s*DIM + l];
  __syncthreads();   // single-wave block: folds to cheap wave-level sync

  // ---- Phase 1: layer 1 ----
  const float* r0 = W1 + l*DIM;
  const float* r1 = W1 + (l+64)*DIM;
  double z1a = (double)b1[l], z1b = (double)b1[l+64];
  double w1a[8], w1b[8];          // t_z1 = W1[:,8+i]
#pragma unroll
  for (int k2=0; k2<DIM; ++k2){
    double wa = (double)r0[k2], wb = (double)r1[k2];
    z1a = fma(wa, xs[k2], z1a);
    z1b = fma(wb, xs[k2], z1b);
    if (k2 >= 8) { w1a[k2-8] = wa; w1b[k2-8] = wb; }
  }
  double s1a = sigd(z1a), s1b = sigd(z1b);
  buf[l] = spd(z1a); buf[l+64] = spd(z1b);
#pragma unroll
  for (int i=0;i<8;++i){
    buf[(1+i)*VSTR + l]      = s1a*w1a[i];
    buf[(1+i)*VSTR + l + 64] = s1b*w1b[i];
  }
  __syncthreads();

  double A9[NVEC], B9[NVEC];

  // ---- Phase 2: layer 2 forward (PF2) ----
  gemv9d(g_ws + 0, buf, l, A9, B9);
  double z2a = A9[0] + (double)b2[l], z2b = B9[0] + (double)b2[l+64];
  double t2a[8], t2b[8];
#pragma unroll
  for (int i=0;i<8;++i){ t2a[i]=A9[1+i]; t2b[i]=B9[1+i]; }
  double s2a = sigd(z2a), s2b = sigd(z2b);
  buf[l] = spd(z2a); buf[l+64] = spd(z2b);
#pragma unroll
  for (int i=0;i<8;++i){
    buf[(1+i)*VSTR + l]      = s2a*t2a[i];
    buf[(1+i)*VSTR + l + 64] = s2b*t2b[i];
  }
  __syncthreads();

  // ---- Phase 3: layer 3 forward (PF3) ----
  gemv9d(g_ws + 32768, buf, l, A9, B9);
  double z3a = A9[0] + (double)b3[l], z3b = B9[0] + (double)b3[l+64];
  double t3a[8], t3b[8];
#pragma unroll
  for (int i=0;i<8;++i){ t3a[i]=A9[1+i]; t3b[i]=B9[1+i]; }
  double s3a = sigd(z3a), s3b = sigd(z3b);
  buf[l] = spd(z3a); buf[l+64] = spd(z3b);
#pragma unroll
  for (int i=0;i<8;++i){
    buf[(1+i)*VSTR + l]      = s3a*t3a[i];
    buf[(1+i)*VSTR + l + 64] = s3b*t3b[i];
  }
  __syncthreads();

  // ---- Phase 4: layer 4 forward (PF4) ----
  gemv9d(g_ws + 65536, buf, l, A9, B9);
  double z4a = A9[0] + (double)b4[l], z4b = B9[0] + (double)b4[l+64];

  // ---- Phase 5: head ----
  {
    double w5a = (double)W5[l], w5b = (double)W5[l+64];
    double sa = sigd(z4a), sb = sigd(z4b);
    buf[l] = w5a*sa; buf[l+64] = w5b*sb;                   // g_z4
    double ca = w5a*sa*(1.0-sa), cb = w5b*sb*(1.0-sb);     // W5*sig'(z4)
#pragma unroll
    for (int i=0;i<8;++i){
      buf[(1+i)*VSTR + l]      = ca*A9[1+i];               // u_z4
      buf[(1+i)*VSTR + l + 64] = cb*B9[1+i];
    }
  }
  __syncthreads();

  // ---- Phase 6: backward through W4^T (PB4) ----
  gemv9d(g_ws + 81920, buf, l, A9, B9);
  {
    double da = s3a*(1.0-s3a)*A9[0], db = s3b*(1.0-s3b)*B9[0];
    buf[l] = A9[0]*s3a; buf[l+64] = B9[0]*s3b;                  // g_z3
#pragma unroll
    for (int i=0;i<8;++i){
      buf[(1+i)*VSTR + l]      = fma(A9[1+i], s3a, da*t3a[i]);  // u_z3
      buf[(1+i)*VSTR + l + 64] = fma(B9[1+i], s3b, db*t3b[i]);
    }
  }
  __syncthreads();

  // ---- Phase 7: backward through W3^T (PB3) ----
  gemv9d(g_ws + 49152, buf, l, A9, B9);
  {
    double da = s2a*(1.0-s2a)*A9[0], db = s2b*(1.0-s2b)*B9[0];
    buf[l] = A9[0]*s2a; buf[l+64] = B9[0]*s2b;                  // g_z2
#pragma unroll
    for (int i=0;i<8;++i){
      buf[(1+i)*VSTR + l]      = fma(A9[1+i], s2a, da*t2a[i]);  // u_z2
      buf[(1+i)*VSTR + l + 64] = fma(B9[1+i], s2b, db*t2b[i]);
    }
  }
  __syncthreads();

  // ---- Phase 8: backward through W2^T (PB2) ----
  gemv9d(g_ws + 16384, buf, l, A9, B9);
  {
    double da = s1a*(1.0-s1a)*A9[0], db = s1b*(1.0-s1b)*B9[0];
    buf[l] = A9[0]*s1a; buf[l+64] = B9[0]*s1b;                  // g_z1
#pragma unroll
    for (int i=0;i<8;++i){
      buf[(1+i)*VSTR + l]      = fma(A9[1+i], s1a, da*w1a[i]);  // u_z1
      buf[(1+i)*VSTR + l + 64] = fma(B9[1+i], s1b, db*w1b[i]);
    }
  }
  __syncthreads();

  // ---- Phase 9: H rows (8..15) + J via W1^T (PB1) ----
  {
    const int m = l & 15, d = l >> 4;
    const double2* P1 = (const double2*)(g_ws + 98304);
    double hA=0.0, hB=0.0, hJ=0.0;
#pragma unroll 4
    for (int q=0; q<64; ++q){
      double2 wq = P1[q*DIM + m];   // {W1[2q][m], W1[2q+1][m]}
      double2 u0 = *((const double2*)(buf + (1+d)*VSTR + 2*q));
      double2 u1 = *((const double2*)(buf + (5+d)*VSTR + 2*q));
      double2 gg = *((const double2*)(buf + 2*q));
      hA = fma(wq.y, u0.y, fma(wq.x, u0.x, hA));
      hB = fma(wq.y, u1.y, fma(wq.x, u1.x, hB));
      hJ = fma(wq.y, gg.y, fma(wq.x, gg.x, hJ));
    }
    hr[d*17+m] = hA;                  // hr[i*17+m] = H[8+i][m]
    hr[(d+4)*17+m] = hB;
    if (d==0) hr[8*17+m] = hJ;        // J[m]
  }
  __syncthreads();

  // ---- Phase 10: y = pinv(B) @ (J[:8] - C qdot), JAX pinv semantics ----
  // Parallel-order (round-robin) Jacobi: 4 disjoint pairs/step, 7 steps/sweep, 6 sweeps.
  {
    const int r = l >> 3, c = l & 7;
    double Bv = hr[r*17 + 8 + c];     // B[r][c]
    double Cr = hr[r*17 + c];         // C[r][c]
    double Jr = hr[8*17 + r];         // A[r]
    double p0 = Cr * xs[8 + c];
    p0 += __shfl_xor(p0, 1); p0 += __shfl_xor(p0, 2); p0 += __shfl_xor(p0, 4);
    double rhs = Jr - p0;             // all lanes of row r hold rhs_r

    // symmetrize
    double Bt = __shfl(Bv, c*8 + r);
    double Am = 0.5*(Bv + Bt);
    double Vm = (r == c) ? 1.0 : 0.0;

    for (int sweep = 0; sweep < 6; ++sweep) {
#pragma unroll
      for (int rr = 0; rr < 7; ++rr) {
        // round-robin partner of this lane's column / row
        int pc = (c == 7) ? rr : ((c == rr) ? 7 : (2*rr + 7 - c) % 7);
        int cp = min(c, pc), cq = max(c, pc);
        double App = __shfl(Am, cp*8+cp);
        double Aqq = __shfl(Am, cq*8+cq);
        double Apq = __shfl(Am, cp*8+cq);
        double tau = (Aqq - App) / (2.0*Apq);
        double tt  = (tau >= 0.0 ? 1.0 : -1.0) / (fabs(tau) + sqrt(1.0 + tau*tau));
        double cth = 1.0 / sqrt(1.0 + tt*tt);
        double sth = tt * cth;
        if (fabs(Apq) < 1e-300) { cth = 1.0; sth = 0.0; }   // guard 0/0 -> NaN
        // row-pair angle: fetched from diagonal lane (r,r), whose column pair contains r
        double cthr = __shfl(cth, r*8+r);
        double sthr = __shfl(sth, r*8+r);
        // column rotation: M = A*G
        double Arp = __shfl(Am, r*8+cp);
        double Arq = __shfl(Am, r*8+cq);
        double colv = (c == cp) ? (cth*Arp - sth*Arq) : (sth*Arp + cth*Arq);
        // row rotation: A = G^T*M
        int pr2 = (r == 7) ? rr : ((r == rr) ? 7 : (2*rr + 7 - r) % 7);
        int rp = min(r, pr2), rq = max(r, pr2);
        double Mpc = __shfl(colv, rp*8+c);
        double Mqc = __shfl(colv, rq*8+c);
        Am = (r == rp) ? (cthr*Mpc - sthr*Mqc) : (sthr*Mpc + cthr*Mqc);
        // V = V*G
        double Vrp = __shfl(Vm, r*8+cp);
        double Vrq = __shfl(Vm, r*8+cq);
        Vm = (c == cp) ? (cth*Vrp - sth*Vrq) : (sth*Vrp + cth*Vrq);
      }
    }

    // eigenvalue for this lane's column, and sigma_max = max |diag|
    double lam_c = __shfl(Am, c*8 + c);
    double adiag = (r == c) ? fabs(Am) : 0.0;
#pragma unroll
    for (int off = 32; off; off >>= 1) adiag = fmax(adiag, __shfl_xor(adiag, off));
    double cutoff = 9.5367431640625e-06 * adiag;   // 10*max(M,N)*eps_f32 * sigma_max

    // p_c = sum_r V[r][c]*rhs_r
    double pr = Vm * rhs;
    pr += __shfl_xor(pr, 8); pr += __shfl_xor(pr, 16); pr += __shfl_xor(pr, 32);
    double w = (fabs(lam_c) > cutoff) ? (pr / lam_c) : 0.0;
    // y_r = sum_c V[r][c]*w_c
    double yr = Vm * w;
    yr += __shfl_xor(yr, 1); yr += __shfl_xor(yr, 2); yr += __shfl_xor(yr, 4);
    if (c == 0) out[s*NPAR + r] = (float)yr;
  }
}

extern "C" void kernel_launch(void* const* d_in, const int* in_sizes, int n_in,
                              void* d_out, int out_size, void* d_ws, size_t ws_size,
                              hipStream_t stream) {
  (void)in_sizes; (void)n_in; (void)out_size; (void)d_ws; (void)ws_size;
  const float* x  = (const float*)d_in[0];
  const float* W1 = (const float*)d_in[1];
  const float* b1 = (const float*)d_in[2];
  const float* W2 = (const float*)d_in[3];
  const float* b2 = (const float*)d_in[4];
  const float* W3 = (const float*)d_in[5];
  const float* b3 = (const float*)d_in[6];
  const float* W4 = (const float*)d_in[7];
  const float* b4 = (const float*)d_in[8];
  const float* W5 = (const float*)d_in[9];
  float* out = (float*)d_out;

  pack_weights<<<200, 256, 0, stream>>>(W1, W2, W3, W4);
  lnn_main<<<BATCH, 64, 0, stream>>>(x, W1, b1, b2, b3, b4, W5, out);
}

// Round 6
// 395.545 us; speedup vs baseline: 1.4840x; 1.4063x over previous
//
#include <hip/hip_runtime.h>
#include <math.h>

#define NPAR 8
#define DIM  16
#define HID  128
#define BATCH 4096
#define VSTR 132               // padded stride (doubles): de-aliases phase-9 d-group banks
#define NVEC 9                 // base + 8 tangent directions

// Packed fp64 weights in static device memory.
// Layout (double offsets): PF2@0 PB2@16384 PF3@32768 PB3@49152 PF4@65536 PB4@81920 PB1@98304
__device__ double g_ws[6*HID*HID + HID*DIM];

__device__ __forceinline__ double sigd(double z){ return 1.0/(1.0+exp(-z)); }
__device__ __forceinline__ double spd(double z){ return fmax(z,0.0)+log1p(exp(-fabs(z))); }

// PF[q][j][kk] = W[j][2q+kk]  (forward GEMV)   PB[q][j][kk] = W[2q+kk][j]  (W^T GEMV)
// PB1[q][m][kk] = W1[2q+kk][m]
__global__ void pack_weights(const float* __restrict__ W1, const float* __restrict__ W2,
                             const float* __restrict__ W3, const float* __restrict__ W4) {
  int t = blockIdx.x*blockDim.x + threadIdx.x;
  if (t < 3*HID*HID) {
    int m = t/(HID*HID); int r = t%(HID*HID);
    int j = r/HID, k = r%HID;
    const float* W = (m==0)?W2:((m==1)?W3:W4);
    double w = (double)W[j*HID+k];
    double* PF = g_ws + m*2*HID*HID;
    double* PB = PF + HID*HID;
    PF[(k>>1)*(HID*2) + j*2 + (k&1)] = w;
    PB[(j>>1)*(HID*2) + k*2 + (j&1)] = w;
  } else {
    int r = t - 3*HID*HID;
    if (r < HID*DIM) {
      int k = r/DIM, m2 = r%DIM;
      g_ws[6*HID*HID + (k>>1)*(DIM*2) + m2*2 + (k&1)] = (double)W1[k*DIM+m2];
    }
  }
}

// Fused 9-vector fp64 GEMV: acc{A,B}[v] = (W @ bin_v)[l], (W @ bin_v)[l+64]
__device__ __forceinline__ void gemv9d(const double* __restrict__ Wbase,
                                       const double* bin, int l,
                                       double* accA, double* accB) {
  const double2* Wq = (const double2*)Wbase;
#pragma unroll
  for (int v=0; v<NVEC; ++v){ accA[v]=0.0; accB[v]=0.0; }
#pragma unroll 2
  for (int q=0; q<HID/2; ++q){
    double2 wA = Wq[q*HID + l];
    double2 wB = Wq[q*HID + l + 64];
#pragma unroll
    for (int v=0; v<NVEC; ++v){
      double2 h = *((const double2*)(bin + v*VSTR + 2*q));  // LDS broadcast (conflict-free)
      accA[v] = fma(wA.y, h.y, fma(wA.x, h.x, accA[v]));
      accB[v] = fma(wB.y, h.y, fma(wB.x, h.x, accB[v]));
    }
  }
}

__global__ __launch_bounds__(64)
__attribute__((amdgpu_waves_per_eu(3, 4)))
void lnn_main(const float* __restrict__ x, const float* __restrict__ W1,
              const float* __restrict__ b1, const float* __restrict__ b2,
              const float* __restrict__ b3, const float* __restrict__ b4,
              const float* __restrict__ W5, float* __restrict__ out) {
  const int l = threadIdx.x;           // one wave per block
  const int s = blockIdx.x;            // one sample per wave

  __shared__ __align__(16) double buf[NVEC*VSTR];  // single in-place buffer
  __shared__ __align__(16) double hr[160];         // H-rows + J scratch
  __shared__ double xs[16];

  if (l < DIM) xs[l] = (double)x[s*DIM + l];
  __syncthreads();

  // ---- Phase 1: layer 1 (W1 rows loaded transiently; reloaded again in phase 8) ----
  const float4* W1v = (const float4*)W1;           // row j = 4 float4s
  double z1a, z1b;
  {
    float4 a0 = W1v[l*4+0], a1 = W1v[l*4+1], a2 = W1v[l*4+2], a3 = W1v[l*4+3];
    float4 c0 = W1v[(l+64)*4+0], c1 = W1v[(l+64)*4+1], c2 = W1v[(l+64)*4+2], c3 = W1v[(l+64)*4+3];
    z1a = (double)b1[l];  z1b = (double)b1[l+64];
    const float* pa = (const float*)&a0;   // a0..a3 contiguous? not guaranteed; do explicit
    (void)pa;
    z1a = fma((double)a0.x, xs[0],  z1a); z1a = fma((double)a0.y, xs[1],  z1a);
    z1a = fma((double)a0.z, xs[2],  z1a); z1a = fma((double)a0.w, xs[3],  z1a);
    z1a = fma((double)a1.x, xs[4],  z1a); z1a = fma((double)a1.y, xs[5],  z1a);
    z1a = fma((double)a1.z, xs[6],  z1a); z1a = fma((double)a1.w, xs[7],  z1a);
    z1a = fma((double)a2.x, xs[8],  z1a); z1a = fma((double)a2.y, xs[9],  z1a);
    z1a = fma((double)a2.z, xs[10], z1a); z1a = fma((double)a2.w, xs[11], z1a);
    z1a = fma((double)a3.x, xs[12], z1a); z1a = fma((double)a3.y, xs[13], z1a);
    z1a = fma((double)a3.z, xs[14], z1a); z1a = fma((double)a3.w, xs[15], z1a);
    z1b = fma((double)c0.x, xs[0],  z1b); z1b = fma((double)c0.y, xs[1],  z1b);
    z1b = fma((double)c0.z, xs[2],  z1b); z1b = fma((double)c0.w, xs[3],  z1b);
    z1b = fma((double)c1.x, xs[4],  z1b); z1b = fma((double)c1.y, xs[5],  z1b);
    z1b = fma((double)c1.z, xs[6],  z1b); z1b = fma((double)c1.w, xs[7],  z1b);
    z1b = fma((double)c2.x, xs[8],  z1b); z1b = fma((double)c2.y, xs[9],  z1b);
    z1b = fma((double)c2.z, xs[10], z1b); z1b = fma((double)c2.w, xs[11], z1b);
    z1b = fma((double)c3.x, xs[12], z1b); z1b = fma((double)c3.y, xs[13], z1b);
    z1b = fma((double)c3.z, xs[14], z1b); z1b = fma((double)c3.w, xs[15], z1b);
    double sa = sigd(z1a), sb = sigd(z1b);
    buf[l] = spd(z1a); buf[l+64] = spd(z1b);
    float wa[8] = {a2.x,a2.y,a2.z,a2.w,a3.x,a3.y,a3.z,a3.w};
    float wb[8] = {c2.x,c2.y,c2.z,c2.w,c3.x,c3.y,c3.z,c3.w};
#pragma unroll
    for (int i=0;i<8;++i){
      buf[(1+i)*VSTR + l]      = sa*(double)wa[i];   // t_h1 = sig(z1)*W1[:,8+i]
      buf[(1+i)*VSTR + l + 64] = sb*(double)wb[i];
    }
  }
  double s1a = sigd(z1a), s1b = sigd(z1b);   // cheap recompute keeps live range small
  __syncthreads();

  double A9[NVEC], B9[NVEC];

  // ---- Phase 2: layer 2 forward (PF2) ----
  gemv9d(g_ws + 0, buf, l, A9, B9);
  double z2a = A9[0] + (double)b2[l], z2b = B9[0] + (double)b2[l+64];
  float t2a[8], t2b[8];                      // f32 storage: sheds 32 VGPRs
#pragma unroll
  for (int i=0;i<8;++i){ t2a[i]=(float)A9[1+i]; t2b[i]=(float)B9[1+i]; }
  double s2a = sigd(z2a), s2b = sigd(z2b);
  buf[l] = spd(z2a); buf[l+64] = spd(z2b);
#pragma unroll
  for (int i=0;i<8;++i){
    buf[(1+i)*VSTR + l]      = s2a*A9[1+i];
    buf[(1+i)*VSTR + l + 64] = s2b*B9[1+i];
  }
  __syncthreads();

  // ---- Phase 3: layer 3 forward (PF3) ----
  gemv9d(g_ws + 32768, buf, l, A9, B9);
  double z3a = A9[0] + (double)b3[l], z3b = B9[0] + (double)b3[l+64];
  float t3a[8], t3b[8];
#pragma unroll
  for (int i=0;i<8;++i){ t3a[i]=(float)A9[1+i]; t3b[i]=(float)B9[1+i]; }
  double s3a = sigd(z3a), s3b = sigd(z3b);
  buf[l] = spd(z3a); buf[l+64] = spd(z3b);
#pragma unroll
  for (int i=0;i<8;++i){
    buf[(1+i)*VSTR + l]      = s3a*A9[1+i];
    buf[(1+i)*VSTR + l + 64] = s3b*B9[1+i];
  }
  __syncthreads();

  // ---- Phase 4: layer 4 forward (PF4) ----
  gemv9d(g_ws + 65536, buf, l, A9, B9);
  double z4a = A9[0] + (double)b4[l], z4b = B9[0] + (double)b4[l+64];

  // ---- Phase 5: head ----
  {
    double w5a = (double)W5[l], w5b = (double)W5[l+64];
    double sa = sigd(z4a), sb = sigd(z4b);
    buf[l] = w5a*sa; buf[l+64] = w5b*sb;                   // g_z4
    double ca = w5a*sa*(1.0-sa), cb = w5b*sb*(1.0-sb);     // W5*sig'(z4)
#pragma unroll
    for (int i=0;i<8;++i){
      buf[(1+i)*VSTR + l]      = ca*A9[1+i];               // u_z4
      buf[(1+i)*VSTR + l + 64] = cb*B9[1+i];
    }
  }
  __syncthreads();

  // ---- Phase 6: backward through W4^T (PB4) ----
  gemv9d(g_ws + 81920, buf, l, A9, B9);
  {
    double da = s3a*(1.0-s3a)*A9[0], db = s3b*(1.0-s3b)*B9[0];
    buf[l] = A9[0]*s3a; buf[l+64] = B9[0]*s3b;                  // g_z3
#pragma unroll
    for (int i=0;i<8;++i){
      buf[(1+i)*VSTR + l]      = fma(A9[1+i], s3a, da*(double)t3a[i]);  // u_z3
      buf[(1+i)*VSTR + l + 64] = fma(B9[1+i], s3b, db*(double)t3b[i]);
    }
  }
  __syncthreads();

  // ---- Phase 7: backward through W3^T (PB3) ----
  gemv9d(g_ws + 49152, buf, l, A9, B9);
  {
    double da = s2a*(1.0-s2a)*A9[0], db = s2b*(1.0-s2b)*B9[0];
    buf[l] = A9[0]*s2a; buf[l+64] = B9[0]*s2b;                  // g_z2
#pragma unroll
    for (int i=0;i<8;++i){
      buf[(1+i)*VSTR + l]      = fma(A9[1+i], s2a, da*(double)t2a[i]);  // u_z2
      buf[(1+i)*VSTR + l + 64] = fma(B9[1+i], s2b, db*(double)t2b[i]);
    }
  }
  __syncthreads();

  // ---- Phase 8: backward through W2^T (PB2); W1 tangent cols reloaded (L2-hot) ----
  gemv9d(g_ws + 16384, buf, l, A9, B9);
  {
    float4 a2 = W1v[l*4+2], a3 = W1v[l*4+3];          // W1 row l, cols 8..15
    float4 c2 = W1v[(l+64)*4+2], c3 = W1v[(l+64)*4+3];
    float wa[8] = {a2.x,a2.y,a2.z,a2.w,a3.x,a3.y,a3.z,a3.w};
    float wb[8] = {c2.x,c2.y,c2.z,c2.w,c3.x,c3.y,c3.z,c3.w};
    double da = s1a*(1.0-s1a)*A9[0], db = s1b*(1.0-s1b)*B9[0];
    buf[l] = A9[0]*s1a; buf[l+64] = B9[0]*s1b;                  // g_z1
#pragma unroll
    for (int i=0;i<8;++i){
      buf[(1+i)*VSTR + l]      = fma(A9[1+i], s1a, da*(double)wa[i]);  // u_z1
      buf[(1+i)*VSTR + l + 64] = fma(B9[1+i], s1b, db*(double)wb[i]);
    }
  }
  __syncthreads();

  // ---- Phase 9: H rows (8..15) + J via W1^T (PB1) ----
  {
    const int m = l & 15, d = l >> 4;
    const double2* P1 = (const double2*)(g_ws + 98304);
    double hA=0.0, hB=0.0, hJ=0.0;
#pragma unroll 4
    for (int q=0; q<64; ++q){
      double2 wq = P1[q*DIM + m];   // {W1[2q][m], W1[2q+1][m]}
      double2 u0 = *((const double2*)(buf + (1+d)*VSTR + 2*q));
      double2 u1 = *((const double2*)(buf + (5+d)*VSTR + 2*q));
      double2 gg = *((const double2*)(buf + 2*q));
      hA = fma(wq.y, u0.y, fma(wq.x, u0.x, hA));
      hB = fma(wq.y, u1.y, fma(wq.x, u1.x, hB));
      hJ = fma(wq.y, gg.y, fma(wq.x, gg.x, hJ));
    }
    hr[d*17+m] = hA;                  // hr[i*17+m] = H[8+i][m]
    hr[(d+4)*17+m] = hB;
    if (d==0) hr[8*17+m] = hJ;        // J[m]
  }
  __syncthreads();

  // ---- Phase 10: y = pinv(B) @ (J[:8] - C qdot), JAX pinv semantics ----
  // Parallel-order (round-robin) Jacobi: 4 disjoint pairs/step, 7 steps/sweep, 6 sweeps.
  {
    const int r = l >> 3, c = l & 7;
    double Bv = hr[r*17 + 8 + c];     // B[r][c]
    double Cr = hr[r*17 + c];         // C[r][c]
    double Jr = hr[8*17 + r];         // A[r]
    double p0 = Cr * xs[8 + c];
    p0 += __shfl_xor(p0, 1); p0 += __shfl_xor(p0, 2); p0 += __shfl_xor(p0, 4);
    double rhs = Jr - p0;             // all lanes of row r hold rhs_r

    // symmetrize
    double Bt = __shfl(Bv, c*8 + r);
    double Am = 0.5*(Bv + Bt);
    double Vm = (r == c) ? 1.0 : 0.0;

    for (int sweep = 0; sweep < 6; ++sweep) {
#pragma unroll
      for (int rr = 0; rr < 7; ++rr) {
        int pc = (c == 7) ? rr : ((c == rr) ? 7 : (2*rr + 7 - c) % 7);
        int cp = min(c, pc), cq = max(c, pc);
        double App = __shfl(Am, cp*8+cp);
        double Aqq = __shfl(Am, cq*8+cq);
        double Apq = __shfl(Am, cp*8+cq);
        double tau = (Aqq - App) / (2.0*Apq);
        double tt  = (tau >= 0.0 ? 1.0 : -1.0) / (fabs(tau) + sqrt(1.0 + tau*tau));
        double cth = 1.0 / sqrt(1.0 + tt*tt);
        double sth = tt * cth;
        if (fabs(Apq) < 1e-300) { cth = 1.0; sth = 0.0; }   // guard 0/0 -> NaN
        double cthr = __shfl(cth, r*8+r);
        double sthr = __shfl(sth, r*8+r);
        // column rotation: M = A*G
        double Arp = __shfl(Am, r*8+cp);
        double Arq = __shfl(Am, r*8+cq);
        double colv = (c == cp) ? (cth*Arp - sth*Arq) : (sth*Arp + cth*Arq);
        // row rotation: A = G^T*M
        int pr2 = (r == 7) ? rr : ((r == rr) ? 7 : (2*rr + 7 - r) % 7);
        int rp = min(r, pr2), rq = max(r, pr2);
        double Mpc = __shfl(colv, rp*8+c);
        double Mqc = __shfl(colv, rq*8+c);
        Am = (r == rp) ? (cthr*Mpc - sthr*Mqc) : (sthr*Mpc + cthr*Mqc);
        // V = V*G
        double Vrp = __shfl(Vm, r*8+cp);
        double Vrq = __shfl(Vm, r*8+cq);
        Vm = (c == cp) ? (cth*Vrp - sth*Vrq) : (sth*Vrp + cth*Vrq);
      }
    }

    // eigenvalue for this lane's column, and sigma_max = max |diag|
    double lam_c = __shfl(Am, c*8 + c);
    double adiag = (r == c) ? fabs(Am) : 0.0;
#pragma unroll
    for (int off = 32; off; off >>= 1) adiag = fmax(adiag, __shfl_xor(adiag, off));
    double cutoff = 9.5367431640625e-06 * adiag;   // 10*max(M,N)*eps_f32 * sigma_max

    // p_c = sum_r V[r][c]*rhs_r
    double pr = Vm * rhs;
    pr += __shfl_xor(pr, 8); pr += __shfl_xor(pr, 16); pr += __shfl_xor(pr, 32);
    double w = (fabs(lam_c) > cutoff) ? (pr / lam_c) : 0.0;
    // y_r = sum_c V[r][c]*w_c
    double yr = Vm * w;
    yr += __shfl_xor(yr, 1); yr += __shfl_xor(yr, 2); yr += __shfl_xor(yr, 4);
    if (c == 0) out[s*NPAR + r] = (float)yr;
  }
}

extern "C" void kernel_launch(void* const* d_in, const int* in_sizes, int n_in,
                              void* d_out, int out_size, void* d_ws, size_t ws_size,
                              hipStream_t stream) {
  (void)in_sizes; (void)n_in; (void)out_size; (void)d_ws; (void)ws_size;
  const float* x  = (const float*)d_in[0];
  const float* W1 = (const float*)d_in[1];
  const float* b1 = (const float*)d_in[2];
  const float* W2 = (const float*)d_in[3];
  const float* b2 = (const float*)d_in[4];
  const float* W3 = (const float*)d_in[5];
  const float* b3 = (const float*)d_in[6];
  const float* W4 = (const float*)d_in[7];
  const float* b4 = (const float*)d_in[8];
  const float* W5 = (const float*)d_in[9];
  float* out = (float*)d_out;

  pack_weights<<<200, 256, 0, stream>>>(W1, W2, W3, W4);
  lnn_main<<<BATCH, 64, 0, stream>>>(x, W1, b1, b2, b3, b4, W5, out);
}

// Round 7
// 362.562 us; speedup vs baseline: 1.6190x; 1.0910x over previous
//
#include <hip/hip_runtime.h>
#include <math.h>

#define NPAR 8
#define DIM  16
#define HID  128
#define BATCH 4096
#define VSTR 132               // padded stride (doubles) for 128-vectors in LDS
#define NVEC 9                 // base + 8 tangent directions

// Packed f32 weights (exact copies of f32 inputs) in static device memory.
// 3.15 MB total -> fits per-XCD 4 MiB L2. Arithmetic stays fp64 (cvt on load, exact).
// Layout (float offsets): PF2@0 PB2@16384 PF3@32768 PB3@49152 PF4@65536 PB4@81920 PB1@98304
__device__ float g_wsf[6*HID*HID + HID*DIM];

__device__ __forceinline__ double sigd(double z){ return 1.0/(1.0+exp(-z)); }
__device__ __forceinline__ double spd(double z){ return fmax(z,0.0)+log1p(exp(-fabs(z))); }

// PF[q4][j][kk] = W[j][4q4+kk]  (forward GEMV)   PB[q4][j][kk] = W[4q4+kk][j]  (W^T GEMV)
// PB1[q4][m][kk] = W1[4q4+kk][m]
__global__ void pack_weights(const float* __restrict__ W1, const float* __restrict__ W2,
                             const float* __restrict__ W3, const float* __restrict__ W4) {
  int t = blockIdx.x*blockDim.x + threadIdx.x;
  if (t < 3*HID*HID) {
    int m = t/(HID*HID); int r = t%(HID*HID);
    int j = r/HID, k = r%HID;
    const float* W = (m==0)?W2:((m==1)?W3:W4);
    float w = W[j*HID+k];
    float* PF = g_wsf + m*2*HID*HID;
    float* PB = PF + HID*HID;
    PF[(k>>2)*(HID*4) + j*4 + (k&3)] = w;
    PB[(j>>2)*(HID*4) + k*4 + (j&3)] = w;
  } else {
    int r = t - 3*HID*HID;
    if (r < HID*DIM) {
      int k = r/DIM, m2 = r%DIM;
      g_wsf[6*HID*HID + (k>>2)*(DIM*4) + m2*4 + (k&3)] = W1[k*DIM+m2];
    }
  }
}

// Fused 9-vector GEMV: f32 weights (exact), fp64 accumulation.
// acc{A,B}[v] = (W @ bin_v)[l], (W @ bin_v)[l+64]
__device__ __forceinline__ void gemv9f(const float* __restrict__ Wbase,
                                       const double* bin, int l,
                                       double* accA, double* accB) {
  const float4* Wq = (const float4*)Wbase;
#pragma unroll
  for (int v=0; v<NVEC; ++v){ accA[v]=0.0; accB[v]=0.0; }
#pragma unroll 2
  for (int q=0; q<HID/4; ++q){
    float4 wA = Wq[q*HID + l];        // W rows l / l+64, k = 4q..4q+3
    float4 wB = Wq[q*HID + l + 64];
    double wa0=(double)wA.x, wa1=(double)wA.y, wa2=(double)wA.z, wa3=(double)wA.w;
    double wb0=(double)wB.x, wb1=(double)wB.y, wb2=(double)wB.z, wb3=(double)wB.w;
#pragma unroll
    for (int v=0; v<NVEC; ++v){
      const double2* hp = (const double2*)(bin + v*VSTR + 4*q);  // LDS broadcast
      double2 h0 = hp[0], h1 = hp[1];
      accA[v] = fma(wa3,h1.y, fma(wa2,h1.x, fma(wa1,h0.y, fma(wa0,h0.x, accA[v]))));
      accB[v] = fma(wb3,h1.y, fma(wb2,h1.x, fma(wb1,h0.y, fma(wb0,h0.x, accB[v]))));
    }
  }
}

__global__ __launch_bounds__(64)
__attribute__((amdgpu_waves_per_eu(3, 4)))
void lnn_main(const float* __restrict__ x, const float* __restrict__ W1,
              const float* __restrict__ b1, const float* __restrict__ b2,
              const float* __restrict__ b3, const float* __restrict__ b4,
              const float* __restrict__ W5, float* __restrict__ out) {
  const int l = threadIdx.x;           // one wave per block
  const int s = blockIdx.x;            // one sample per wave

  __shared__ __align__(16) double buf[NVEC*VSTR];  // single in-place buffer
  __shared__ double xs[16];

  if (l < DIM) xs[l] = (double)x[s*DIM + l];
  __syncthreads();

  // ---- Phase 1: layer 1 (W1 rows loaded transiently; reloaded in phase 8) ----
  const float4* W1v = (const float4*)W1;           // row j = 4 float4s
  double z1a, z1b;
  {
    float4 a0 = W1v[l*4+0], a1 = W1v[l*4+1], a2 = W1v[l*4+2], a3 = W1v[l*4+3];
    float4 c0 = W1v[(l+64)*4+0], c1 = W1v[(l+64)*4+1], c2 = W1v[(l+64)*4+2], c3 = W1v[(l+64)*4+3];
    z1a = (double)b1[l];  z1b = (double)b1[l+64];
    z1a = fma((double)a0.x, xs[0],  z1a); z1a = fma((double)a0.y, xs[1],  z1a);
    z1a = fma((double)a0.z, xs[2],  z1a); z1a = fma((double)a0.w, xs[3],  z1a);
    z1a = fma((double)a1.x, xs[4],  z1a); z1a = fma((double)a1.y, xs[5],  z1a);
    z1a = fma((double)a1.z, xs[6],  z1a); z1a = fma((double)a1.w, xs[7],  z1a);
    z1a = fma((double)a2.x, xs[8],  z1a); z1a = fma((double)a2.y, xs[9],  z1a);
    z1a = fma((double)a2.z, xs[10], z1a); z1a = fma((double)a2.w, xs[11], z1a);
    z1a = fma((double)a3.x, xs[12], z1a); z1a = fma((double)a3.y, xs[13], z1a);
    z1a = fma((double)a3.z, xs[14], z1a); z1a = fma((double)a3.w, xs[15], z1a);
    z1b = fma((double)c0.x, xs[0],  z1b); z1b = fma((double)c0.y, xs[1],  z1b);
    z1b = fma((double)c0.z, xs[2],  z1b); z1b = fma((double)c0.w, xs[3],  z1b);
    z1b = fma((double)c1.x, xs[4],  z1b); z1b = fma((double)c1.y, xs[5],  z1b);
    z1b = fma((double)c1.z, xs[6],  z1b); z1b = fma((double)c1.w, xs[7],  z1b);
    z1b = fma((double)c2.x, xs[8],  z1b); z1b = fma((double)c2.y, xs[9],  z1b);
    z1b = fma((double)c2.z, xs[10], z1b); z1b = fma((double)c2.w, xs[11], z1b);
    z1b = fma((double)c3.x, xs[12], z1b); z1b = fma((double)c3.y, xs[13], z1b);
    z1b = fma((double)c3.z, xs[14], z1b); z1b = fma((double)c3.w, xs[15], z1b);
    double sa = sigd(z1a), sb = sigd(z1b);
    buf[l] = spd(z1a); buf[l+64] = spd(z1b);
    float wa[8] = {a2.x,a2.y,a2.z,a2.w,a3.x,a3.y,a3.z,a3.w};
    float wb[8] = {c2.x,c2.y,c2.z,c2.w,c3.x,c3.y,c3.z,c3.w};
#pragma unroll
    for (int i=0;i<8;++i){
      buf[(1+i)*VSTR + l]      = sa*(double)wa[i];   // t_h1 = sig(z1)*W1[:,8+i]
      buf[(1+i)*VSTR + l + 64] = sb*(double)wb[i];
    }
  }
  double s1a = sigd(z1a), s1b = sigd(z1b);   // cheap recompute keeps live range small
  __syncthreads();

  double A9[NVEC], B9[NVEC];

  // ---- Phase 2: layer 2 forward (PF2) ----
  gemv9f(g_wsf + 0, buf, l, A9, B9);
  double z2a = A9[0] + (double)b2[l], z2b = B9[0] + (double)b2[l+64];
  float t2a[8], t2b[8];                      // f32 tangent cache (sheds VGPRs)
#pragma unroll
  for (int i=0;i<8;++i){ t2a[i]=(float)A9[1+i]; t2b[i]=(float)B9[1+i]; }
  double s2a = sigd(z2a), s2b = sigd(z2b);
  buf[l] = spd(z2a); buf[l+64] = spd(z2b);
#pragma unroll
  for (int i=0;i<8;++i){
    buf[(1+i)*VSTR + l]      = s2a*A9[1+i];
    buf[(1+i)*VSTR + l + 64] = s2b*B9[1+i];
  }
  __syncthreads();

  // ---- Phase 3: layer 3 forward (PF3) ----
  gemv9f(g_wsf + 32768, buf, l, A9, B9);
  double z3a = A9[0] + (double)b3[l], z3b = B9[0] + (double)b3[l+64];
  float t3a[8], t3b[8];
#pragma unroll
  for (int i=0;i<8;++i){ t3a[i]=(float)A9[1+i]; t3b[i]=(float)B9[1+i]; }
  double s3a = sigd(z3a), s3b = sigd(z3b);
  buf[l] = spd(z3a); buf[l+64] = spd(z3b);
#pragma unroll
  for (int i=0;i<8;++i){
    buf[(1+i)*VSTR + l]      = s3a*A9[1+i];
    buf[(1+i)*VSTR + l + 64] = s3b*B9[1+i];
  }
  __syncthreads();

  // ---- Phase 4: layer 4 forward (PF4) ----
  gemv9f(g_wsf + 65536, buf, l, A9, B9);
  double z4a = A9[0] + (double)b4[l], z4b = B9[0] + (double)b4[l+64];

  // ---- Phase 5: head ----
  {
    double w5a = (double)W5[l], w5b = (double)W5[l+64];
    double sa = sigd(z4a), sb = sigd(z4b);
    buf[l] = w5a*sa; buf[l+64] = w5b*sb;                   // g_z4
    double ca = w5a*sa*(1.0-sa), cb = w5b*sb*(1.0-sb);     // W5*sig'(z4)
#pragma unroll
    for (int i=0;i<8;++i){
      buf[(1+i)*VSTR + l]      = ca*A9[1+i];               // u_z4
      buf[(1+i)*VSTR + l + 64] = cb*B9[1+i];
    }
  }
  __syncthreads();

  // ---- Phase 6: backward through W4^T (PB4) ----
  gemv9f(g_wsf + 81920, buf, l, A9, B9);
  {
    double da = s3a*(1.0-s3a)*A9[0], db = s3b*(1.0-s3b)*B9[0];
    buf[l] = A9[0]*s3a; buf[l+64] = B9[0]*s3b;                  // g_z3
#pragma unroll
    for (int i=0;i<8;++i){
      buf[(1+i)*VSTR + l]      = fma(A9[1+i], s3a, da*(double)t3a[i]);  // u_z3
      buf[(1+i)*VSTR + l + 64] = fma(B9[1+i], s3b, db*(double)t3b[i]);
    }
  }
  __syncthreads();

  // ---- Phase 7: backward through W3^T (PB3) ----
  gemv9f(g_wsf + 49152, buf, l, A9, B9);
  {
    double da = s2a*(1.0-s2a)*A9[0], db = s2b*(1.0-s2b)*B9[0];
    buf[l] = A9[0]*s2a; buf[l+64] = B9[0]*s2b;                  // g_z2
#pragma unroll
    for (int i=0;i<8;++i){
      buf[(1+i)*VSTR + l]      = fma(A9[1+i], s2a, da*(double)t2a[i]);  // u_z2
      buf[(1+i)*VSTR + l + 64] = fma(B9[1+i], s2b, db*(double)t2b[i]);
    }
  }
  __syncthreads();

  // ---- Phase 8: backward through W2^T (PB2); W1 tangent cols reloaded (L2-hot) ----
  gemv9f(g_wsf + 16384, buf, l, A9, B9);
  {
    float4 a2 = W1v[l*4+2], a3 = W1v[l*4+3];          // W1 row l, cols 8..15
    float4 c2 = W1v[(l+64)*4+2], c3 = W1v[(l+64)*4+3];
    float wa[8] = {a2.x,a2.y,a2.z,a2.w,a3.x,a3.y,a3.z,a3.w};
    float wb[8] = {c2.x,c2.y,c2.z,c2.w,c3.x,c3.y,c3.z,c3.w};
    double da = s1a*(1.0-s1a)*A9[0], db = s1b*(1.0-s1b)*B9[0];
    buf[l] = A9[0]*s1a; buf[l+64] = B9[0]*s1b;                  // g_z1
#pragma unroll
    for (int i=0;i<8;++i){
      buf[(1+i)*VSTR + l]      = fma(A9[1+i], s1a, da*(double)wa[i]);  // u_z1
      buf[(1+i)*VSTR + l + 64] = fma(B9[1+i], s1b, db*(double)wb[i]);
    }
  }
  __syncthreads();

  // ---- Phase 9: H rows (8..15) + J via W1^T (PB1), results stay in registers ----
  double hA, hB, hJ;
  {
    const int m = l & 15, d = l >> 4;
    const float4* P1 = (const float4*)(g_wsf + 98304);
    hA=0.0; hB=0.0; hJ=0.0;
#pragma unroll 2
    for (int q=0; q<32; ++q){
      float4 wq = P1[q*DIM + m];   // W1[4q..4q+3][m]
      double w0=(double)wq.x, w1=(double)wq.y, w2=(double)wq.z, w3=(double)wq.w;
      const double2* u0p = (const double2*)(buf + (1+d)*VSTR + 4*q);
      const double2* u1p = (const double2*)(buf + (5+d)*VSTR + 4*q);
      const double2* ggp = (const double2*)(buf + 4*q);
      double2 u00=u0p[0], u01=u0p[1], u10=u1p[0], u11=u1p[1], g0=ggp[0], g1=ggp[1];
      hA = fma(w3,u01.y, fma(w2,u01.x, fma(w1,u00.y, fma(w0,u00.x, hA))));
      hB = fma(w3,u11.y, fma(w2,u11.x, fma(w1,u10.y, fma(w0,u10.x, hB))));
      hJ = fma(w3,g1.y,  fma(w2,g1.x,  fma(w1,g0.y,  fma(w0,g0.x,  hJ))));
    }
    // lane (m,d) holds hA = H[8+d][m], hB = H[8+4+d][m], hJ = J[m]
  }

  // ---- Phase 10: y = pinv(B) @ (J[:8] - C qdot); B/C/J gathered via shuffles ----
  {
    const int r = l >> 3, c = l & 7;
    // H[8+i][j]: i<4 -> hA@lane(i*16+j), i>=4 -> hB@lane((i-4)*16+j)
    double BvA = __shfl(hA, ((r&3)*16) + 8 + c);
    double BvB = __shfl(hB, ((r&3)*16) + 8 + c);
    double Bv  = (r < 4) ? BvA : BvB;            // B[r][c] = H[8+r][8+c]
    double CrA = __shfl(hA, ((r&3)*16) + c);
    double CrB = __shfl(hB, ((r&3)*16) + c);
    double Cr  = (r < 4) ? CrA : CrB;            // C[r][c] = H[8+r][c]
    double Jr  = __shfl(hJ, r);                  // J[r]
    double p0 = Cr * xs[8 + c];
    p0 += __shfl_xor(p0, 1); p0 += __shfl_xor(p0, 2); p0 += __shfl_xor(p0, 4);
    double rhs = Jr - p0;             // all lanes of row r hold rhs_r

    // symmetrize
    double Bt = __shfl(Bv, c*8 + r);
    double Am = 0.5*(Bv + Bt);
    double Vm = (r == c) ? 1.0 : 0.0;

    // Parallel-order (round-robin) Jacobi: 4 disjoint pairs/step, 7 steps/sweep, 6 sweeps.
    for (int sweep = 0; sweep < 6; ++sweep) {
#pragma unroll
      for (int rr = 0; rr < 7; ++rr) {
        int pc = (c == 7) ? rr : ((c == rr) ? 7 : (2*rr + 7 - c) % 7);
        int cp = min(c, pc), cq = max(c, pc);
        double App = __shfl(Am, cp*8+cp);
        double Aqq = __shfl(Am, cq*8+cq);
        double Apq = __shfl(Am, cp*8+cq);
        double tau = (Aqq - App) / (2.0*Apq);
        double tt  = (tau >= 0.0 ? 1.0 : -1.0) / (fabs(tau) + sqrt(1.0 + tau*tau));
        double cth = 1.0 / sqrt(1.0 + tt*tt);
        double sth = tt * cth;
        if (fabs(Apq) < 1e-300) { cth = 1.0; sth = 0.0; }   // guard 0/0 -> NaN
        double cthr = __shfl(cth, r*8+r);
        double sthr = __shfl(sth, r*8+r);
        // column rotation: M = A*G
        double Arp = __shfl(Am, r*8+cp);
        double Arq = __shfl(Am, r*8+cq);
        double colv = (c == cp) ? (cth*Arp - sth*Arq) : (sth*Arp + cth*Arq);
        // row rotation: A = G^T*M
        int pr2 = (r == 7) ? rr : ((r == rr) ? 7 : (2*rr + 7 - r) % 7);
        int rp = min(r, pr2), rq = max(r, pr2);
        double Mpc = __shfl(colv, rp*8+c);
        double Mqc = __shfl(colv, rq*8+c);
        Am = (r == rp) ? (cthr*Mpc - sthr*Mqc) : (sthr*Mpc + cthr*Mqc);
        // V = V*G
        double Vrp = __shfl(Vm, r*8+cp);
        double Vrq = __shfl(Vm, r*8+cq);
        Vm = (c == cp) ? (cth*Vrp - sth*Vrq) : (sth*Vrp + cth*Vrq);
      }
    }

    // eigenvalue for this lane's column, and sigma_max = max |diag|
    double lam_c = __shfl(Am, c*8 + c);
    double adiag = (r == c) ? fabs(Am) : 0.0;
#pragma unroll
    for (int off = 32; off; off >>= 1) adiag = fmax(adiag, __shfl_xor(adiag, off));
    double cutoff = 9.5367431640625e-06 * adiag;   // 10*max(M,N)*eps_f32 * sigma_max

    // p_c = sum_r V[r][c]*rhs_r
    double pr = Vm * rhs;
    pr += __shfl_xor(pr, 8); pr += __shfl_xor(pr, 16); pr += __shfl_xor(pr, 32);
    double w = (fabs(lam_c) > cutoff) ? (pr / lam_c) : 0.0;
    // y_r = sum_c V[r][c]*w_c
    double yr = Vm * w;
    yr += __shfl_xor(yr, 1); yr += __shfl_xor(yr, 2); yr += __shfl_xor(yr, 4);
    if (c == 0) out[s*NPAR + r] = (float)yr;
  }
}

extern "C" void kernel_launch(void* const* d_in, const int* in_sizes, int n_in,
                              void* d_out, int out_size, void* d_ws, size_t ws_size,
                              hipStream_t stream) {
  (void)in_sizes; (void)n_in; (void)out_size; (void)d_ws; (void)ws_size;
  const float* x  = (const float*)d_in[0];
  const float* W1 = (const float*)d_in[1];
  const float* b1 = (const float*)d_in[2];
  const float* W2 = (const float*)d_in[3];
  const float* b2 = (const float*)d_in[4];
  const float* W3 = (const float*)d_in[5];
  const float* b3 = (const float*)d_in[6];
  const float* W4 = (const float*)d_in[7];
  const float* b4 = (const float*)d_in[8];
  const float* W5 = (const float*)d_in[9];
  float* out = (float*)d_out;

  pack_weights<<<200, 256, 0, stream>>>(W1, W2, W3, W4);
  lnn_main<<<BATCH, 64, 0, stream>>>(x, W1, b1, b2, b3, b4, W5, out);
}

// Round 8
// 359.948 us; speedup vs baseline: 1.6308x; 1.0073x over previous
//
#include <hip/hip_runtime.h>
#include <math.h>

#define NPAR 8
#define DIM  16
#define HID  128
#define BATCH 4096
#define SPB  4                 // samples (waves) per 256-thread block
#define VSTR 132               // padded stride (doubles) for 128-vectors in LDS
#define NVEC 9                 // base + 8 tangent directions
#define BUFSZ (NVEC*VSTR)      // 1188 doubles per wave

// Packed f32 weights (exact copies of f32 inputs) in static device memory.
// 3.15 MB total -> fits per-XCD 4 MiB L2. Arithmetic stays fp64 (cvt on load, exact).
// Layout (float offsets): PF2@0 PB2@16384 PF3@32768 PB3@49152 PF4@65536 PB4@81920 PB1@98304
__device__ float g_wsf[6*HID*HID + HID*DIM];

__device__ __forceinline__ double sigd(double z){ return 1.0/(1.0+exp(-z)); }
__device__ __forceinline__ double spd(double z){ return fmax(z,0.0)+log1p(exp(-fabs(z))); }

// PF[q4][j][kk] = W[j][4q4+kk]  (forward GEMV)   PB[q4][j][kk] = W[4q4+kk][j]  (W^T GEMV)
// PB1[q4][m][kk] = W1[4q4+kk][m]
__global__ void pack_weights(const float* __restrict__ W1, const float* __restrict__ W2,
                             const float* __restrict__ W3, const float* __restrict__ W4) {
  int t = blockIdx.x*blockDim.x + threadIdx.x;
  if (t < 3*HID*HID) {
    int m = t/(HID*HID); int r = t%(HID*HID);
    int j = r/HID, k = r%HID;
    const float* W = (m==0)?W2:((m==1)?W3:W4);
    float w = W[j*HID+k];
    float* PF = g_wsf + m*2*HID*HID;
    float* PB = PF + HID*HID;
    PF[(k>>2)*(HID*4) + j*4 + (k&3)] = w;
    PB[(j>>2)*(HID*4) + k*4 + (j&3)] = w;
  } else {
    int r = t - 3*HID*HID;
    if (r < HID*DIM) {
      int k = r/DIM, m2 = r%DIM;
      g_wsf[6*HID*HID + (k>>2)*(DIM*4) + m2*4 + (k&3)] = W1[k*DIM+m2];
    }
  }
}

// Fused 9-vector GEMV: f32 weights (exact), fp64 accumulation.
// acc{A,B}[v] = (W @ bin_v)[l], (W @ bin_v)[l+64]
__device__ __forceinline__ void gemv9f(const float* __restrict__ Wbase,
                                       const double* bin, int l,
                                       double* accA, double* accB) {
  const float4* Wq = (const float4*)Wbase;
#pragma unroll
  for (int v=0; v<NVEC; ++v){ accA[v]=0.0; accB[v]=0.0; }
#pragma unroll 4
  for (int q=0; q<HID/4; ++q){
    float4 wA = Wq[q*HID + l];        // W rows l / l+64, k = 4q..4q+3
    float4 wB = Wq[q*HID + l + 64];
    double wa0=(double)wA.x, wa1=(double)wA.y, wa2=(double)wA.z, wa3=(double)wA.w;
    double wb0=(double)wB.x, wb1=(double)wB.y, wb2=(double)wB.z, wb3=(double)wB.w;
#pragma unroll
    for (int v=0; v<NVEC; ++v){
      const double2* hp = (const double2*)(bin + v*VSTR + 4*q);  // LDS broadcast
      double2 h0 = hp[0], h1 = hp[1];
      accA[v] = fma(wa3,h1.y, fma(wa2,h1.x, fma(wa1,h0.y, fma(wa0,h0.x, accA[v]))));
      accB[v] = fma(wb3,h1.y, fma(wb2,h1.x, fma(wb1,h0.y, fma(wb0,h0.x, accB[v]))));
    }
  }
}

__global__ __launch_bounds__(256)
__attribute__((amdgpu_waves_per_eu(3, 4)))
void lnn_main(const float* __restrict__ x, const float* __restrict__ W1,
              const float* __restrict__ b1, const float* __restrict__ b2,
              const float* __restrict__ b3, const float* __restrict__ b4,
              const float* __restrict__ W5, float* __restrict__ out) {
  const int l  = threadIdx.x & 63;     // lane
  const int wv = threadIdx.x >> 6;     // wave in block
  const int s  = blockIdx.x*SPB + wv;  // one sample per wave

  __shared__ __align__(16) double smem[SPB*BUFSZ];
  __shared__ double xsm[SPB*16];
  double* buf = smem + wv*BUFSZ;       // private per-wave slice
  double* xs  = xsm + wv*16;

  if (l < DIM) xs[l] = (double)x[s*DIM + l];
  __syncthreads();

  // ---- Phase 1: layer 1 (W1 rows loaded transiently; reloaded in phase 8) ----
  const float4* W1v = (const float4*)W1;           // row j = 4 float4s
  double z1a, z1b;
  {
    float4 a0 = W1v[l*4+0], a1 = W1v[l*4+1], a2 = W1v[l*4+2], a3 = W1v[l*4+3];
    float4 c0 = W1v[(l+64)*4+0], c1 = W1v[(l+64)*4+1], c2 = W1v[(l+64)*4+2], c3 = W1v[(l+64)*4+3];
    z1a = (double)b1[l];  z1b = (double)b1[l+64];
    z1a = fma((double)a0.x, xs[0],  z1a); z1a = fma((double)a0.y, xs[1],  z1a);
    z1a = fma((double)a0.z, xs[2],  z1a); z1a = fma((double)a0.w, xs[3],  z1a);
    z1a = fma((double)a1.x, xs[4],  z1a); z1a = fma((double)a1.y, xs[5],  z1a);
    z1a = fma((double)a1.z, xs[6],  z1a); z1a = fma((double)a1.w, xs[7],  z1a);
    z1a = fma((double)a2.x, xs[8],  z1a); z1a = fma((double)a2.y, xs[9],  z1a);
    z1a = fma((double)a2.z, xs[10], z1a); z1a = fma((double)a2.w, xs[11], z1a);
    z1a = fma((double)a3.x, xs[12], z1a); z1a = fma((double)a3.y, xs[13], z1a);
    z1a = fma((double)a3.z, xs[14], z1a); z1a = fma((double)a3.w, xs[15], z1a);
    z1b = fma((double)c0.x, xs[0],  z1b); z1b = fma((double)c0.y, xs[1],  z1b);
    z1b = fma((double)c0.z, xs[2],  z1b); z1b = fma((double)c0.w, xs[3],  z1b);
    z1b = fma((double)c1.x, xs[4],  z1b); z1b = fma((double)c1.y, xs[5],  z1b);
    z1b = fma((double)c1.z, xs[6],  z1b); z1b = fma((double)c1.w, xs[7],  z1b);
    z1b = fma((double)c2.x, xs[8],  z1b); z1b = fma((double)c2.y, xs[9],  z1b);
    z1b = fma((double)c2.z, xs[10], z1b); z1b = fma((double)c2.w, xs[11], z1b);
    z1b = fma((double)c3.x, xs[12], z1b); z1b = fma((double)c3.y, xs[13], z1b);
    z1b = fma((double)c3.z, xs[14], z1b); z1b = fma((double)c3.w, xs[15], z1b);
    double sa = sigd(z1a), sb = sigd(z1b);
    buf[l] = spd(z1a); buf[l+64] = spd(z1b);
    float wa[8] = {a2.x,a2.y,a2.z,a2.w,a3.x,a3.y,a3.z,a3.w};
    float wb[8] = {c2.x,c2.y,c2.z,c2.w,c3.x,c3.y,c3.z,c3.w};
#pragma unroll
    for (int i=0;i<8;++i){
      buf[(1+i)*VSTR + l]      = sa*(double)wa[i];   // t_h1 = sig(z1)*W1[:,8+i]
      buf[(1+i)*VSTR + l + 64] = sb*(double)wb[i];
    }
  }
  double s1a = sigd(z1a), s1b = sigd(z1b);   // cheap recompute keeps live range small
  __syncthreads();

  double A9[NVEC], B9[NVEC];

  // ---- Phase 2: layer 2 forward (PF2) ----
  gemv9f(g_wsf + 0, buf, l, A9, B9);
  double z2a = A9[0] + (double)b2[l], z2b = B9[0] + (double)b2[l+64];
  float t2a[8], t2b[8];                      // f32 tangent cache (sheds VGPRs)
#pragma unroll
  for (int i=0;i<8;++i){ t2a[i]=(float)A9[1+i]; t2b[i]=(float)B9[1+i]; }
  double s2a = sigd(z2a), s2b = sigd(z2b);
  buf[l] = spd(z2a); buf[l+64] = spd(z2b);
#pragma unroll
  for (int i=0;i<8;++i){
    buf[(1+i)*VSTR + l]      = s2a*A9[1+i];
    buf[(1+i)*VSTR + l + 64] = s2b*B9[1+i];
  }
  __syncthreads();

  // ---- Phase 3: layer 3 forward (PF3) ----
  gemv9f(g_wsf + 32768, buf, l, A9, B9);
  double z3a = A9[0] + (double)b3[l], z3b = B9[0] + (double)b3[l+64];
  float t3a[8], t3b[8];
#pragma unroll
  for (int i=0;i<8;++i){ t3a[i]=(float)A9[1+i]; t3b[i]=(float)B9[1+i]; }
  double s3a = sigd(z3a), s3b = sigd(z3b);
  buf[l] = spd(z3a); buf[l+64] = spd(z3b);
#pragma unroll
  for (int i=0;i<8;++i){
    buf[(1+i)*VSTR + l]      = s3a*A9[1+i];
    buf[(1+i)*VSTR + l + 64] = s3b*B9[1+i];
  }
  __syncthreads();

  // ---- Phase 4: layer 4 forward (PF4) ----
  gemv9f(g_wsf + 65536, buf, l, A9, B9);
  double z4a = A9[0] + (double)b4[l], z4b = B9[0] + (double)b4[l+64];

  // ---- Phase 5: head ----
  {
    double w5a = (double)W5[l], w5b = (double)W5[l+64];
    double sa = sigd(z4a), sb = sigd(z4b);
    buf[l] = w5a*sa; buf[l+64] = w5b*sb;                   // g_z4
    double ca = w5a*sa*(1.0-sa), cb = w5b*sb*(1.0-sb);     // W5*sig'(z4)
#pragma unroll
    for (int i=0;i<8;++i){
      buf[(1+i)*VSTR + l]      = ca*A9[1+i];               // u_z4
      buf[(1+i)*VSTR + l + 64] = cb*B9[1+i];
    }
  }
  __syncthreads();

  // ---- Phase 6: backward through W4^T (PB4) ----
  gemv9f(g_wsf + 81920, buf, l, A9, B9);
  {
    double da = s3a*(1.0-s3a)*A9[0], db = s3b*(1.0-s3b)*B9[0];
    buf[l] = A9[0]*s3a; buf[l+64] = B9[0]*s3b;                  // g_z3
#pragma unroll
    for (int i=0;i<8;++i){
      buf[(1+i)*VSTR + l]      = fma(A9[1+i], s3a, da*(double)t3a[i]);  // u_z3
      buf[(1+i)*VSTR + l + 64] = fma(B9[1+i], s3b, db*(double)t3b[i]);
    }
  }
  __syncthreads();

  // ---- Phase 7: backward through W3^T (PB3) ----
  gemv9f(g_wsf + 49152, buf, l, A9, B9);
  {
    double da = s2a*(1.0-s2a)*A9[0], db = s2b*(1.0-s2b)*B9[0];
    buf[l] = A9[0]*s2a; buf[l+64] = B9[0]*s2b;                  // g_z2
#pragma unroll
    for (int i=0;i<8;++i){
      buf[(1+i)*VSTR + l]      = fma(A9[1+i], s2a, da*(double)t2a[i]);  // u_z2
      buf[(1+i)*VSTR + l + 64] = fma(B9[1+i], s2b, db*(double)t2b[i]);
    }
  }
  __syncthreads();

  // ---- Phase 8: backward through W2^T (PB2); W1 tangent cols reloaded (L2-hot) ----
  gemv9f(g_wsf + 16384, buf, l, A9, B9);
  {
    float4 a2 = W1v[l*4+2], a3 = W1v[l*4+3];          // W1 row l, cols 8..15
    float4 c2 = W1v[(l+64)*4+2], c3 = W1v[(l+64)*4+3];
    float wa[8] = {a2.x,a2.y,a2.z,a2.w,a3.x,a3.y,a3.z,a3.w};
    float wb[8] = {c2.x,c2.y,c2.z,c2.w,c3.x,c3.y,c3.z,c3.w};
    double da = s1a*(1.0-s1a)*A9[0], db = s1b*(1.0-s1b)*B9[0];
    buf[l] = A9[0]*s1a; buf[l+64] = B9[0]*s1b;                  // g_z1
#pragma unroll
    for (int i=0;i<8;++i){
      buf[(1+i)*VSTR + l]      = fma(A9[1+i], s1a, da*(double)wa[i]);  // u_z1
      buf[(1+i)*VSTR + l + 64] = fma(B9[1+i], s1b, db*(double)wb[i]);
    }
  }
  __syncthreads();

  // ---- Phase 9: H rows (8..15) + J via W1^T (PB1), results stay in registers ----
  double hA, hB, hJ;
  {
    const int m = l & 15, d = l >> 4;
    const float4* P1 = (const float4*)(g_wsf + 98304);
    hA=0.0; hB=0.0; hJ=0.0;
#pragma unroll 4
    for (int q=0; q<32; ++q){
      float4 wq = P1[q*DIM + m];   // W1[4q..4q+3][m]
      double w0=(double)wq.x, w1=(double)wq.y, w2=(double)wq.z, w3=(double)wq.w;
      const double2* u0p = (const double2*)(buf + (1+d)*VSTR + 4*q);
      const double2* u1p = (const double2*)(buf + (5+d)*VSTR + 4*q);
      const double2* ggp = (const double2*)(buf + 4*q);
      double2 u00=u0p[0], u01=u0p[1], u10=u1p[0], u11=u1p[1], g0=ggp[0], g1=ggp[1];
      hA = fma(w3,u01.y, fma(w2,u01.x, fma(w1,u00.y, fma(w0,u00.x, hA))));
      hB = fma(w3,u11.y, fma(w2,u11.x, fma(w1,u10.y, fma(w0,u10.x, hB))));
      hJ = fma(w3,g1.y,  fma(w2,g1.x,  fma(w1,g0.y,  fma(w0,g0.x,  hJ))));
    }
    // lane (m,d) holds hA = H[8+d][m], hB = H[8+4+d][m], hJ = J[m]
  }

  // ---- Phase 10: y = pinv(B) @ (J[:8] - C qdot); B/C/J gathered via shuffles ----
  {
    const int r = l >> 3, c = l & 7;
    // H[8+i][j]: i<4 -> hA@lane(i*16+j), i>=4 -> hB@lane((i-4)*16+j)
    double BvA = __shfl(hA, ((r&3)*16) + 8 + c);
    double BvB = __shfl(hB, ((r&3)*16) + 8 + c);
    double Bv  = (r < 4) ? BvA : BvB;            // B[r][c] = H[8+r][8+c]
    double CrA = __shfl(hA, ((r&3)*16) + c);
    double CrB = __shfl(hB, ((r&3)*16) + c);
    double Cr  = (r < 4) ? CrA : CrB;            // C[r][c] = H[8+r][c]
    double Jr  = __shfl(hJ, r);                  // J[r]
    double p0 = Cr * xs[8 + c];
    p0 += __shfl_xor(p0, 1); p0 += __shfl_xor(p0, 2); p0 += __shfl_xor(p0, 4);
    double rhs = Jr - p0;             // all lanes of row r hold rhs_r

    // symmetrize
    double Bt = __shfl(Bv, c*8 + r);
    double Am = 0.5*(Bv + Bt);
    double Vm = (r == c) ? 1.0 : 0.0;

    // Parallel-order (round-robin) Jacobi: 4 disjoint pairs/step, 7 steps/sweep, 6 sweeps.
    for (int sweep = 0; sweep < 6; ++sweep) {
#pragma unroll
      for (int rr = 0; rr < 7; ++rr) {
        int pc = (c == 7) ? rr : ((c == rr) ? 7 : (2*rr + 7 - c) % 7);
        int cp = min(c, pc), cq = max(c, pc);
        double App = __shfl(Am, cp*8+cp);
        double Aqq = __shfl(Am, cq*8+cq);
        double Apq = __shfl(Am, cp*8+cq);
        double tau = (Aqq - App) / (2.0*Apq);
        double tt  = (tau >= 0.0 ? 1.0 : -1.0) / (fabs(tau) + sqrt(1.0 + tau*tau));
        double cth = 1.0 / sqrt(1.0 + tt*tt);
        double sth = tt * cth;
        if (fabs(Apq) < 1e-300) { cth = 1.0; sth = 0.0; }   // guard 0/0 -> NaN
        double cthr = __shfl(cth, r*8+r);
        double sthr = __shfl(sth, r*8+r);
        // column rotation: M = A*G
        double Arp = __shfl(Am, r*8+cp);
        double Arq = __shfl(Am, r*8+cq);
        double colv = (c == cp) ? (cth*Arp - sth*Arq) : (sth*Arp + cth*Arq);
        // row rotation: A = G^T*M
        int pr2 = (r == 7) ? rr : ((r == rr) ? 7 : (2*rr + 7 - r) % 7);
        int rp = min(r, pr2), rq = max(r, pr2);
        double Mpc = __shfl(colv, rp*8+c);
        double Mqc = __shfl(colv, rq*8+c);
        Am = (r == rp) ? (cthr*Mpc - sthr*Mqc) : (sthr*Mpc + cthr*Mqc);
        // V = V*G
        double Vrp = __shfl(Vm, r*8+cp);
        double Vrq = __shfl(Vm, r*8+cq);
        Vm = (c == cp) ? (cth*Vrp - sth*Vrq) : (sth*Vrp + cth*Vrq);
      }
    }

    // eigenvalue for this lane's column, and sigma_max = max |diag|
    double lam_c = __shfl(Am, c*8 + c);
    double adiag = (r == c) ? fabs(Am) : 0.0;
#pragma unroll
    for (int off = 32; off; off >>= 1) adiag = fmax(adiag, __shfl_xor(adiag, off));
    double cutoff = 9.5367431640625e-06 * adiag;   // 10*max(M,N)*eps_f32 * sigma_max

    // p_c = sum_r V[r][c]*rhs_r
    double pr = Vm * rhs;
    pr += __shfl_xor(pr, 8); pr += __shfl_xor(pr, 16); pr += __shfl_xor(pr, 32);
    double w = (fabs(lam_c) > cutoff) ? (pr / lam_c) : 0.0;
    // y_r = sum_c V[r][c]*w_c
    double yr = Vm * w;
    yr += __shfl_xor(yr, 1); yr += __shfl_xor(yr, 2); yr += __shfl_xor(yr, 4);
    if (c == 0) out[s*NPAR + r] = (float)yr;
  }
}

extern "C" void kernel_launch(void* const* d_in, const int* in_sizes, int n_in,
                              void* d_out, int out_size, void* d_ws, size_t ws_size,
                              hipStream_t stream) {
  (void)in_sizes; (void)n_in; (void)out_size; (void)d_ws; (void)ws_size;
  const float* x  = (const float*)d_in[0];
  const float* W1 = (const float*)d_in[1];
  const float* b1 = (const float*)d_in[2];
  const float* W2 = (const float*)d_in[3];
  const float* b2 = (const float*)d_in[4];
  const float* W3 = (const float*)d_in[5];
  const float* b3 = (const float*)d_in[6];
  const float* W4 = (const float*)d_in[7];
  const float* b4 = (const float*)d_in[8];
  const float* W5 = (const float*)d_in[9];
  float* out = (float*)d_out;

  pack_weights<<<200, 256, 0, stream>>>(W1, W2, W3, W4);
  lnn_main<<<BATCH/SPB, 256, 0, stream>>>(x, W1, b1, b2, b3, b4, W5, out);
}

// Round 9
// 315.144 us; speedup vs baseline: 1.8626x; 1.1422x over previous
//
#include <hip/hip_runtime.h>
#include <math.h>

#define NPAR 8
#define DIM  16
#define HID  128
#define BATCH 4096
#define VSTR 132               // padded stride (doubles) for 128-vectors in LDS
#define NVEC 9                 // base + 8 tangent directions

// Packed f32 weights (exact copies of f32 inputs) in static device memory.
// Layout (float offsets): PF2@0 PB2@16384 PF3@32768 PB3@49152 PF4@65536 PB4@81920 PB1@98304
// pos(jo,kr) = (((kr>>6)*16 + ((kr&63)>>2))*4 + (jo>>5))*128 + (jo&31)*4 + (kr&3)
// so lane (o,kh) reads float4 Wq[((kh*16+q)*4+jj)*32 + o] = W-rows {o+32jj}, k=kh*64+4q..+3.
__device__ float g_wsf[6*HID*HID + HID*DIM];

__device__ __forceinline__ double sigd(double z){ return 1.0/(1.0+exp(-z)); }
__device__ __forceinline__ double spd(double z){ return fmax(z,0.0)+log1p(exp(-fabs(z))); }
__device__ __forceinline__ int posf(int jo, int kr){
  return (((kr>>6)*16 + ((kr&63)>>2))*4 + (jo>>5))*128 + (jo&31)*4 + (kr&3);
}

__global__ void pack_weights(const float* __restrict__ W1, const float* __restrict__ W2,
                             const float* __restrict__ W3, const float* __restrict__ W4) {
  int t = blockIdx.x*blockDim.x + threadIdx.x;
  if (t < 3*HID*HID) {
    int m = t/(HID*HID); int r = t%(HID*HID);
    int j = r/HID, k = r%HID;
    const float* W = (m==0)?W2:((m==1)?W3:W4);
    float w = W[j*HID+k];
    float* PF = g_wsf + m*2*HID*HID;
    float* PB = PF + HID*HID;
    PF[posf(j,k)] = w;      // forward: OUT[j] = sum_k W[j][k] h[k]
    PB[posf(k,j)] = w;      // backward: OUT[k] = sum_j W[j][k] h[j]
  } else {
    int r = t - 3*HID*HID;
    if (r < HID*DIM) {
      int k = r/DIM, m2 = r%DIM;
      g_wsf[6*HID*HID + (k>>2)*(DIM*4) + m2*4 + (k&3)] = W1[k*DIM+m2];  // PB1[q][m][kk]=W1[4q+kk][m]
    }
  }
}

// Split-K fused 9-vector GEMV: lane (o,kh) accumulates partial sums over its
// k-half for outputs {o, o+32, o+64, o+96}. f32 weights (exact), fp64 accum.
__device__ __forceinline__ void gemv9s(const float* __restrict__ Wbase,
                                       const double* bin, int o, int kh,
                                       double acc[4][NVEC]) {
  const float4* Wq = (const float4*)Wbase;
  const double* hb = bin + kh*64;
#pragma unroll
  for (int jj=0;jj<4;++jj)
#pragma unroll
    for (int v=0;v<NVEC;++v) acc[jj][v]=0.0;
#pragma unroll 2
  for (int q=0;q<16;++q){
    int base = ((kh*16+q)*4)*32 + o;
    float4 w0 = Wq[base], w1 = Wq[base+32], w2 = Wq[base+64], w3 = Wq[base+96];
    double w00=(double)w0.x,w01=(double)w0.y,w02=(double)w0.z,w03=(double)w0.w;
    double w10=(double)w1.x,w11=(double)w1.y,w12=(double)w1.z,w13=(double)w1.w;
    double w20=(double)w2.x,w21=(double)w2.y,w22=(double)w2.z,w23=(double)w2.w;
    double w30=(double)w3.x,w31=(double)w3.y,w32=(double)w3.z,w33=(double)w3.w;
#pragma unroll
    for (int v=0;v<NVEC;++v){
      const double2* hp = (const double2*)(hb + v*VSTR + 4*q);  // LDS broadcast
      double2 h0 = hp[0], h1 = hp[1];
      acc[0][v] = fma(w03,h1.y, fma(w02,h1.x, fma(w01,h0.y, fma(w00,h0.x, acc[0][v]))));
      acc[1][v] = fma(w13,h1.y, fma(w12,h1.x, fma(w11,h0.y, fma(w10,h0.x, acc[1][v]))));
      acc[2][v] = fma(w23,h1.y, fma(w22,h1.x, fma(w21,h0.y, fma(w20,h0.x, acc[2][v]))));
      acc[3][v] = fma(w33,h1.y, fma(w32,h1.x, fma(w31,h0.y, fma(w30,h0.x, acc[3][v]))));
    }
  }
}

// reduce k-halves and select this lane's two owned outputs (j_a=o+64kh, j_b=j_a+32)
__device__ __forceinline__ void reduce_sel(double acc[4][NVEC], int kh,
                                           double* zA, double* zB) {
#pragma unroll
  for (int v=0;v<NVEC;++v){
    double a0 = acc[0][v] + __shfl_xor(acc[0][v], 32);
    double a1 = acc[1][v] + __shfl_xor(acc[1][v], 32);
    double a2 = acc[2][v] + __shfl_xor(acc[2][v], 32);
    double a3 = acc[3][v] + __shfl_xor(acc[3][v], 32);
    zA[v] = kh ? a2 : a0;
    zB[v] = kh ? a3 : a1;
  }
}

__global__ __launch_bounds__(64)
__attribute__((amdgpu_waves_per_eu(2, 4)))
void lnn_main(const float* __restrict__ x, const float* __restrict__ W1,
              const float* __restrict__ b1, const float* __restrict__ b2,
              const float* __restrict__ b3, const float* __restrict__ b4,
              const float* __restrict__ W5, float* __restrict__ out) {
  const int l  = threadIdx.x;
  const int o  = l & 31;
  const int kh = l >> 5;
  const int ja = o + 64*kh;            // this lane's epilogue outputs
  const int jb = ja + 32;
  const int s  = blockIdx.x;           // one sample per wave

  __shared__ __align__(16) double buf[NVEC*VSTR];
  __shared__ double xs[16];

  if (l < DIM) xs[l] = (double)x[s*DIM + l];
  __syncthreads();

  // ---- Phase 1: layer 1 (rows ja, jb) ----
  const float4* W1v = (const float4*)W1;
  double z1a, z1b;
  float w1af[8], w1bf[8];
  {
    float4 a0 = W1v[ja*4+0], a1 = W1v[ja*4+1], a2 = W1v[ja*4+2], a3 = W1v[ja*4+3];
    float4 c0 = W1v[jb*4+0], c1 = W1v[jb*4+1], c2 = W1v[jb*4+2], c3 = W1v[jb*4+3];
    z1a = (double)b1[ja];  z1b = (double)b1[jb];
    z1a = fma((double)a0.x, xs[0],  z1a); z1a = fma((double)a0.y, xs[1],  z1a);
    z1a = fma((double)a0.z, xs[2],  z1a); z1a = fma((double)a0.w, xs[3],  z1a);
    z1a = fma((double)a1.x, xs[4],  z1a); z1a = fma((double)a1.y, xs[5],  z1a);
    z1a = fma((double)a1.z, xs[6],  z1a); z1a = fma((double)a1.w, xs[7],  z1a);
    z1a = fma((double)a2.x, xs[8],  z1a); z1a = fma((double)a2.y, xs[9],  z1a);
    z1a = fma((double)a2.z, xs[10], z1a); z1a = fma((double)a2.w, xs[11], z1a);
    z1a = fma((double)a3.x, xs[12], z1a); z1a = fma((double)a3.y, xs[13], z1a);
    z1a = fma((double)a3.z, xs[14], z1a); z1a = fma((double)a3.w, xs[15], z1a);
    z1b = fma((double)c0.x, xs[0],  z1b); z1b = fma((double)c0.y, xs[1],  z1b);
    z1b = fma((double)c0.z, xs[2],  z1b); z1b = fma((double)c0.w, xs[3],  z1b);
    z1b = fma((double)c1.x, xs[4],  z1b); z1b = fma((double)c1.y, xs[5],  z1b);
    z1b = fma((double)c1.z, xs[6],  z1b); z1b = fma((double)c1.w, xs[7],  z1b);
    z1b = fma((double)c2.x, xs[8],  z1b); z1b = fma((double)c2.y, xs[9],  z1b);
    z1b = fma((double)c2.z, xs[10], z1b); z1b = fma((double)c2.w, xs[11], z1b);
    z1b = fma((double)c3.x, xs[12], z1b); z1b = fma((double)c3.y, xs[13], z1b);
    z1b = fma((double)c3.z, xs[14], z1b); z1b = fma((double)c3.w, xs[15], z1b);
    double sa = sigd(z1a), sb = sigd(z1b);
    buf[ja] = spd(z1a); buf[jb] = spd(z1b);
    w1af[0]=a2.x; w1af[1]=a2.y; w1af[2]=a2.z; w1af[3]=a2.w;
    w1af[4]=a3.x; w1af[5]=a3.y; w1af[6]=a3.z; w1af[7]=a3.w;
    w1bf[0]=c2.x; w1bf[1]=c2.y; w1bf[2]=c2.z; w1bf[3]=c2.w;
    w1bf[4]=c3.x; w1bf[5]=c3.y; w1bf[6]=c3.z; w1bf[7]=c3.w;
#pragma unroll
    for (int i=0;i<8;++i){
      buf[(1+i)*VSTR + ja] = sa*(double)w1af[i];   // t_h1 = sig(z1)*W1[:,8+i]
      buf[(1+i)*VSTR + jb] = sb*(double)w1bf[i];
    }
  }
  double s1a = sigd(z1a), s1b = sigd(z1b);
  __syncthreads();

  double acc[4][NVEC], zA[NVEC], zB[NVEC];

  // ---- Phase 2: layer 2 forward (PF2) ----
  gemv9s(g_wsf + 0, buf, o, kh, acc);
  reduce_sel(acc, kh, zA, zB);
  double z2a = zA[0] + (double)b2[ja], z2b = zB[0] + (double)b2[jb];
  float t2a[8], t2b[8];
#pragma unroll
  for (int i=0;i<8;++i){ t2a[i]=(float)zA[1+i]; t2b[i]=(float)zB[1+i]; }
  double s2a = sigd(z2a), s2b = sigd(z2b);
  __syncthreads();   // all reads of buf done before overwrite
  buf[ja] = spd(z2a); buf[jb] = spd(z2b);
#pragma unroll
  for (int i=0;i<8;++i){
    buf[(1+i)*VSTR + ja] = s2a*zA[1+i];
    buf[(1+i)*VSTR + jb] = s2b*zB[1+i];
  }
  __syncthreads();

  // ---- Phase 3: layer 3 forward (PF3) ----
  gemv9s(g_wsf + 32768, buf, o, kh, acc);
  reduce_sel(acc, kh, zA, zB);
  double z3a = zA[0] + (double)b3[ja], z3b = zB[0] + (double)b3[jb];
  float t3a[8], t3b[8];
#pragma unroll
  for (int i=0;i<8;++i){ t3a[i]=(float)zA[1+i]; t3b[i]=(float)zB[1+i]; }
  double s3a = sigd(z3a), s3b = sigd(z3b);
  __syncthreads();
  buf[ja] = spd(z3a); buf[jb] = spd(z3b);
#pragma unroll
  for (int i=0;i<8;++i){
    buf[(1+i)*VSTR + ja] = s3a*zA[1+i];
    buf[(1+i)*VSTR + jb] = s3b*zB[1+i];
  }
  __syncthreads();

  // ---- Phase 4+5: layer 4 forward (PF4) + head ----
  gemv9s(g_wsf + 65536, buf, o, kh, acc);
  reduce_sel(acc, kh, zA, zB);
  double z4a = zA[0] + (double)b4[ja], z4b = zB[0] + (double)b4[jb];
  {
    double w5a = (double)W5[ja], w5b = (double)W5[jb];
    double sa = sigd(z4a), sb = sigd(z4b);
    __syncthreads();
    buf[ja] = w5a*sa; buf[jb] = w5b*sb;                   // g_z4
    double ca = w5a*sa*(1.0-sa), cb = w5b*sb*(1.0-sb);    // W5*sig'(z4)
#pragma unroll
    for (int i=0;i<8;++i){
      buf[(1+i)*VSTR + ja] = ca*zA[1+i];                  // u_z4
      buf[(1+i)*VSTR + jb] = cb*zB[1+i];
    }
  }
  __syncthreads();

  // ---- Phase 6: backward through W4^T (PB4) ----
  gemv9s(g_wsf + 81920, buf, o, kh, acc);
  reduce_sel(acc, kh, zA, zB);
  {
    double da = s3a*(1.0-s3a)*zA[0], db = s3b*(1.0-s3b)*zB[0];
    __syncthreads();
    buf[ja] = zA[0]*s3a; buf[jb] = zB[0]*s3b;                   // g_z3
#pragma unroll
    for (int i=0;i<8;++i){
      buf[(1+i)*VSTR + ja] = fma(zA[1+i], s3a, da*(double)t3a[i]);  // u_z3
      buf[(1+i)*VSTR + jb] = fma(zB[1+i], s3b, db*(double)t3b[i]);
    }
  }
  __syncthreads();

  // ---- Phase 7: backward through W3^T (PB3) ----
  gemv9s(g_wsf + 49152, buf, o, kh, acc);
  reduce_sel(acc, kh, zA, zB);
  {
    double da = s2a*(1.0-s2a)*zA[0], db = s2b*(1.0-s2b)*zB[0];
    __syncthreads();
    buf[ja] = zA[0]*s2a; buf[jb] = zB[0]*s2b;                   // g_z2
#pragma unroll
    for (int i=0;i<8;++i){
      buf[(1+i)*VSTR + ja] = fma(zA[1+i], s2a, da*(double)t2a[i]);  // u_z2
      buf[(1+i)*VSTR + jb] = fma(zB[1+i], s2b, db*(double)t2b[i]);
    }
  }
  __syncthreads();

  // ---- Phase 8: backward through W2^T (PB2); W1 tangent cols from phase-1 regs ----
  gemv9s(g_wsf + 16384, buf, o, kh, acc);
  reduce_sel(acc, kh, zA, zB);
  {
    double da = s1a*(1.0-s1a)*zA[0], db = s1b*(1.0-s1b)*zB[0];
    __syncthreads();
    buf[ja] = zA[0]*s1a; buf[jb] = zB[0]*s1b;                   // g_z1
#pragma unroll
    for (int i=0;i<8;++i){
      buf[(1+i)*VSTR + ja] = fma(zA[1+i], s1a, da*(double)w1af[i]);  // u_z1
      buf[(1+i)*VSTR + jb] = fma(zB[1+i], s1b, db*(double)w1bf[i]);
    }
  }
  __syncthreads();

  // ---- Phase 9: H rows (8..15) + J via W1^T (PB1), results stay in registers ----
  double hA, hB, hJ;
  {
    const int m = l & 15, d = l >> 4;
    const float4* P1 = (const float4*)(g_wsf + 98304);
    hA=0.0; hB=0.0; hJ=0.0;
#pragma unroll 4
    for (int q=0; q<32; ++q){
      float4 wq = P1[q*DIM + m];   // W1[4q..4q+3][m]
      double w0=(double)wq.x, w1=(double)wq.y, w2=(double)wq.z, w3=(double)wq.w;
      const double2* u0p = (const double2*)(buf + (1+d)*VSTR + 4*q);
      const double2* u1p = (const double2*)(buf + (5+d)*VSTR + 4*q);
      const double2* ggp = (const double2*)(buf + 4*q);
      double2 u00=u0p[0], u01=u0p[1], u10=u1p[0], u11=u1p[1], g0=ggp[0], g1=ggp[1];
      hA = fma(w3,u01.y, fma(w2,u01.x, fma(w1,u00.y, fma(w0,u00.x, hA))));
      hB = fma(w3,u11.y, fma(w2,u11.x, fma(w1,u10.y, fma(w0,u10.x, hB))));
      hJ = fma(w3,g1.y,  fma(w2,g1.x,  fma(w1,g0.y,  fma(w0,g0.x,  hJ))));
    }
    // lane (m,d) holds hA = H[8+d][m], hB = H[8+4+d][m], hJ = J[m]
  }

  // ---- Phase 10: y = pinv(B) @ (J[:8] - C qdot); B/C/J gathered via shuffles ----
  {
    const int r = l >> 3, c = l & 7;
    double BvA = __shfl(hA, ((r&3)*16) + 8 + c);
    double BvB = __shfl(hB, ((r&3)*16) + 8 + c);
    double Bv  = (r < 4) ? BvA : BvB;            // B[r][c] = H[8+r][8+c]
    double CrA = __shfl(hA, ((r&3)*16) + c);
    double CrB = __shfl(hB, ((r&3)*16) + c);
    double Cr  = (r < 4) ? CrA : CrB;            // C[r][c] = H[8+r][c]
    double Jr  = __shfl(hJ, r);                  // J[r]
    double p0 = Cr * xs[8 + c];
    p0 += __shfl_xor(p0, 1); p0 += __shfl_xor(p0, 2); p0 += __shfl_xor(p0, 4);
    double rhs = Jr - p0;             // all lanes of row r hold rhs_r

    // symmetrize
    double Bt = __shfl(Bv, c*8 + r);
    double Am = 0.5*(Bv + Bt);
    double Vm = (r == c) ? 1.0 : 0.0;

    // Parallel-order (round-robin) Jacobi: 4 disjoint pairs/step, 7 steps/sweep, 6 sweeps.
    for (int sweep = 0; sweep < 6; ++sweep) {
#pragma unroll
      for (int rr = 0; rr < 7; ++rr) {
        int pc = (c == 7) ? rr : ((c == rr) ? 7 : (2*rr + 7 - c) % 7);
        int cp = min(c, pc), cq = max(c, pc);
        double App = __shfl(Am, cp*8+cp);
        double Aqq = __shfl(Am, cq*8+cq);
        double Apq = __shfl(Am, cp*8+cq);
        double tau = (Aqq - App) / (2.0*Apq);
        double tt  = (tau >= 0.0 ? 1.0 : -1.0) / (fabs(tau) + sqrt(1.0 + tau*tau));
        double cth = 1.0 / sqrt(1.0 + tt*tt);
        double sth = tt * cth;
        if (fabs(Apq) < 1e-300) { cth = 1.0; sth = 0.0; }   // guard 0/0 -> NaN
        double cthr = __shfl(cth, r*8+r);
        double sthr = __shfl(sth, r*8+r);
        // column rotation: M = A*G
        double Arp = __shfl(Am, r*8+cp);
        double Arq = __shfl(Am, r*8+cq);
        double colv = (c == cp) ? (cth*Arp - sth*Arq) : (sth*Arp + cth*Arq);
        // row rotation: A = G^T*M
        int pr2 = (r == 7) ? rr : ((r == rr) ? 7 : (2*rr + 7 - r) % 7);
        int rp = min(r, pr2), rq = max(r, pr2);
        double Mpc = __shfl(colv, rp*8+c);
        double Mqc = __shfl(colv, rq*8+c);
        Am = (r == rp) ? (cthr*Mpc - sthr*Mqc) : (sthr*Mpc + cthr*Mqc);
        // V = V*G
        double Vrp = __shfl(Vm, r*8+cp);
        double Vrq = __shfl(Vm, r*8+cq);
        Vm = (c == cp) ? (cth*Vrp - sth*Vrq) : (sth*Vrp + cth*Vrq);
      }
    }

    // eigenvalue for this lane's column, and sigma_max = max |diag|
    double lam_c = __shfl(Am, c*8 + c);
    double adiag = (r == c) ? fabs(Am) : 0.0;
#pragma unroll
    for (int off = 32; off; off >>= 1) adiag = fmax(adiag, __shfl_xor(adiag, off));
    double cutoff = 9.5367431640625e-06 * adiag;   // 10*max(M,N)*eps_f32 * sigma_max

    // p_c = sum_r V[r][c]*rhs_r
    double pr = Vm * rhs;
    pr += __shfl_xor(pr, 8); pr += __shfl_xor(pr, 16); pr += __shfl_xor(pr, 32);
    double w = (fabs(lam_c) > cutoff) ? (pr / lam_c) : 0.0;
    // y_r = sum_c V[r][c]*w_c
    double yr = Vm * w;
    yr += __shfl_xor(yr, 1); yr += __shfl_xor(yr, 2); yr += __shfl_xor(yr, 4);
    if (c == 0) out[s*NPAR + r] = (float)yr;
  }
}

extern "C" void kernel_launch(void* const* d_in, const int* in_sizes, int n_in,
                              void* d_out, int out_size, void* d_ws, size_t ws_size,
                              hipStream_t stream) {
  (void)in_sizes; (void)n_in; (void)out_size; (void)d_ws; (void)ws_size;
  const float* x  = (const float*)d_in[0];
  const float* W1 = (const float*)d_in[1];
  const float* b1 = (const float*)d_in[2];
  const float* W2 = (const float*)d_in[3];
  const float* b2 = (const float*)d_in[4];
  const float* W3 = (const float*)d_in[5];
  const float* b3 = (const float*)d_in[6];
  const float* W4 = (const float*)d_in[7];
  const float* b4 = (const float*)d_in[8];
  const float* W5 = (const float*)d_in[9];
  float* out = (float*)d_out;

  pack_weights<<<200, 256, 0, stream>>>(W1, W2, W3, W4);
  lnn_main<<<BATCH, 64, 0, stream>>>(x, W1, b1, b2, b3, b4, W5, out);
}